// Round 4
// baseline (1075.975 us; speedup 1.0000x reference)
//
#include <hip/hip_runtime.h>
#include <hip/hip_bf16.h>
#include <math.h>

#define DI __device__ __forceinline__

constexpr int cB = 64, cL = 256, cD = 768;
constexpr long BLD = (long)cB * cL * cD;   // 12,582,912
constexpr long BLL = (long)cB * cL * cL;   //  4,194,304

typedef __attribute__((ext_vector_type(8))) short b8;
typedef __attribute__((ext_vector_type(4))) float f4;

// async global->LDS, 16B per lane: LDS dest = base + lane*16, src per-lane addr
DI void gll16(const __hip_bfloat16* g, __hip_bfloat16* l) {
  __builtin_amdgcn_global_load_lds(
      (const __attribute__((address_space(1))) unsigned int*)g,
      (__attribute__((address_space(3))) unsigned int*)l, 16, 0, 0);
}

// ---------------- reductions (wave64) ----------------
DI float wsum(float v) {
#pragma unroll
  for (int o = 32; o > 0; o >>= 1) v += __shfl_down(v, o, 64);
  return v;
}
DI float wsum_all(float v) {
#pragma unroll
  for (int m = 32; m > 0; m >>= 1) v += __shfl_xor(v, m, 64);
  return v;
}
DI float wmax_all(float v) {
#pragma unroll
  for (int m = 32; m > 0; m >>= 1) v = fmaxf(v, __shfl_xor(v, m, 64));
  return v;
}
DI float wmaxr(float v) {
#pragma unroll
  for (int o = 32; o > 0; o >>= 1) v = fmaxf(v, __shfl_down(v, o, 64));
  return v;
}
DI float blockSum(float v) {
  __shared__ float sh[4];
  v = wsum(v);
  __syncthreads();
  if ((threadIdx.x & 63) == 0) sh[threadIdx.x >> 6] = v;
  __syncthreads();
  return sh[0] + sh[1] + sh[2] + sh[3];
}
DI float blockMax(float v) {
  __shared__ float sh[4];
  v = wmaxr(v);
  __syncthreads();
  if ((threadIdx.x & 63) == 0) sh[threadIdx.x >> 6] = v;
  __syncthreads();
  return fmaxf(fmaxf(sh[0], sh[1]), fmaxf(sh[2], sh[3]));
}
DI float sigf(float x) { return 1.f / (1.f + expf(-x)); }

// ================= bf16 MFMA GEMM: C = A(MxK) @ BT(NxK)^T =================
// 128x128 tile, 4 waves, 4x4 of 16x16x32 frags/wave, BK=32.
// Staging via global_load_lds(16B): wave w owns k-chunk w (8 bf16);
// lane l stages row (m0+l) and (m0+64+l). LDS slot(m, q) = (q*129 + m)*8
// (+1-chunk pad per q-block). Frag reads: 16 consecutive 16B chunks/quad.
// EPI: 0=plain (OBF/RELU), 1=I_com (read auxf=Isem, write auxb bf16),
//      2=H-update (relu -> gate vs auxf=H in place, write auxb bf16).
template <int OBF, int RELU, int BIAS, int EPI>
__global__ __launch_bounds__(256, 2) void bgemm(
    const __hip_bfloat16* __restrict__ A, const __hip_bfloat16* __restrict__ BT,
    void* __restrict__ Cv, const float* __restrict__ bias,
    float* __restrict__ auxf, __hip_bfloat16* __restrict__ auxb,
    int K, int lda, int ldb, int ldc,
    int zshift, int zmask, long sA1, long sA2, long sB1, long sB2, long sC) {
  __shared__ __align__(16) __hip_bfloat16 Asp[4 * 129 * 8];
  __shared__ __align__(16) __hip_bfloat16 Bsp[4 * 129 * 8];
  int z = blockIdx.z;
  A += (long)(z >> zshift) * sA1 + (long)(z & zmask) * sA2;
  BT += (long)(z >> zshift) * sB1 + (long)(z & zmask) * sB2;
  int tid = threadIdx.x;
  int lane = tid & 63, w = tid >> 6;
  int wr = w >> 1, wc = w & 1;
  int l16 = lane & 15, q = lane >> 4;
  int m0 = blockIdx.y << 7, n0 = blockIdx.x << 7;

  const __hip_bfloat16* Ag0 = A + (long)(m0 + lane) * lda + w * 8;
  const __hip_bfloat16* Ag1 = Ag0 + 64L * lda;
  const __hip_bfloat16* Bg0 = BT + (long)(n0 + lane) * ldb + w * 8;
  const __hip_bfloat16* Bg1 = Bg0 + 64L * ldb;
  __hip_bfloat16* Al0 = &Asp[(w * 129) * 8];
  __hip_bfloat16* Al1 = &Asp[(w * 129 + 64) * 8];
  __hip_bfloat16* Bl0 = &Bsp[(w * 129) * 8];
  __hip_bfloat16* Bl1 = &Bsp[(w * 129 + 64) * 8];

  f4 acc[4][4];
#pragma unroll
  for (int i = 0; i < 4; i++)
#pragma unroll
    for (int j = 0; j < 4; j++) acc[i][j] = (f4){0.f, 0.f, 0.f, 0.f};

  for (int k0 = 0; k0 < K; k0 += 32) {
    __syncthreads();
    gll16(Ag0 + k0, Al0);
    gll16(Ag1 + k0, Al1);
    gll16(Bg0 + k0, Bl0);
    gll16(Bg1 + k0, Bl1);
    __syncthreads();
    b8 af[4], bf[4];
#pragma unroll
    for (int i = 0; i < 4; i++)
      af[i] = *(const b8*)&Asp[(q * 129 + wr * 64 + i * 16 + l16) * 8];
#pragma unroll
    for (int j = 0; j < 4; j++)
      bf[j] = *(const b8*)&Bsp[(q * 129 + wc * 64 + j * 16 + l16) * 8];
#pragma unroll
    for (int i = 0; i < 4; i++)
#pragma unroll
      for (int j = 0; j < 4; j++)
        acc[i][j] = __builtin_amdgcn_mfma_f32_16x16x32_bf16(af[i], bf[j], acc[i][j], 0, 0, 0);
  }
  long cz = (long)z * sC;
#pragma unroll
  for (int j = 0; j < 4; j++) {
    int n = n0 + wc * 64 + j * 16 + l16;
    float bv = BIAS ? bias[n] : 0.f;
#pragma unroll
    for (int i = 0; i < 4; i++) {
#pragma unroll
      for (int r = 0; r < 4; r++) {
        int m = m0 + wr * 64 + i * 16 + q * 4 + r;
        long idx = cz + (long)m * ldc + n;
        float v = acc[i][j][r] + bv;
        if (EPI == 0) {
          if (RELU) v = fmaxf(v, 0.f);
          if (OBF)
            ((__hip_bfloat16*)Cv)[idx] = __float2bfloat16(v);
          else
            ((float*)Cv)[idx] = v;
        } else if (EPI == 1) {
          // v = I_lat; I_com = Isem + 0.5*sig(v)*(v - Isem)
          float is = auxf[idx];
          float g = 0.5f * sigf(v);
          auxb[idx] = __float2bfloat16(is + g * (v - is));
        } else {
          // v = Hout = relu(acc+bias); H' = H + sig(H)*(Hout - H)
          v = fmaxf(v, 0.f);
          float h = auxf[idx];
          float g = sigf(h);
          float o = h + g * (v - h);
          auxf[idx] = o;
          auxb[idx] = __float2bfloat16(o);
        }
      }
    }
  }
}

// ---------------- weight convert+transpose: dst[n*768+k] = bf16(src[k*768+n]) ----------------
__global__ void k_wconv(const float* __restrict__ src, __hip_bfloat16* __restrict__ dst) {
  __shared__ float t[32][33];
  int k0 = blockIdx.x * 32, n0 = blockIdx.y * 32;
  int tx = threadIdx.x, ty = threadIdx.y;
#pragma unroll
  for (int i = 0; i < 32; i += 8) t[ty + i][tx] = src[(long)(k0 + ty + i) * cD + n0 + tx];
  __syncthreads();
#pragma unroll
  for (int i = 0; i < 32; i += 8)
    dst[(long)(n0 + ty + i) * cD + k0 + tx] = __float2bfloat16(t[tx][ty + i]);
}

// ---------------- bf16 per-batch transpose: (B,L,D) -> (B,D,L) ----------------
__global__ void k_tbf16(const __hip_bfloat16* __restrict__ in, __hip_bfloat16* __restrict__ out) {
  __shared__ __hip_bfloat16 t[32][33];
  int b = blockIdx.z;
  int l0 = blockIdx.x * 32, d0 = blockIdx.y * 32;
  int tx = threadIdx.x, ty = threadIdx.y;
  const __hip_bfloat16* ip = in + (long)b * cL * cD;
  __hip_bfloat16* op = out + (long)b * cL * cD;
#pragma unroll
  for (int i = 0; i < 32; i += 8) t[ty + i][tx] = ip[(long)(l0 + ty + i) * cD + d0 + tx];
  __syncthreads();
#pragma unroll
  for (int i = 0; i < 32; i += 8) op[(long)(d0 + ty + i) * cL + l0 + tx] = t[tx][ty + i];
}

// ---------------- embedding + layernorm; also writes pre-LN x for l==0 ----------------
__global__ __launch_bounds__(256) void k_gcnin(
    const int* __restrict__ tbi, const int* __restrict__ bsi,
    const float* __restrict__ tok, const float* __restrict__ seg,
    const float* __restrict__ ln_a, const float* __restrict__ ln_b,
    float* __restrict__ gcn_in, __hip_bfloat16* __restrict__ gib,
    float* __restrict__ x64) {
  long bl = blockIdx.x;
  int t = tbi[bl], s = bsi[bl];
  const float* tr = tok + (long)t * cD;
  const float* sr = seg + (long)s * cD;
  float x[3];
  float ls = 0.f;
#pragma unroll
  for (int i = 0; i < 3; i++) {
    int d = threadIdx.x + (i << 8);
    x[i] = tr[d] + sr[d];
    ls += x[i];
  }
  if ((bl & 255) == 0) {
#pragma unroll
    for (int i = 0; i < 3; i++) x64[(bl >> 8) * cD + threadIdx.x + (i << 8)] = x[i];
  }
  float mean = blockSum(ls) * (1.f / 768.f);
  float lv = 0.f;
#pragma unroll
  for (int i = 0; i < 3; i++) { float c = x[i] - mean; lv += c * c; }
  float var = blockSum(lv) * (1.f / 767.f);
  float inv = 1.f / (sqrtf(var) + 1e-6f);
#pragma unroll
  for (int i = 0; i < 3; i++) {
    int d = threadIdx.x + (i << 8);
    float v = ln_a[d] * (x[i] - mean) * inv + ln_b[d];
    gcn_in[bl * cD + d] = v;
    gib[bl * cD + d] = __float2bfloat16(v);
  }
}

// ---------------- pooled GEMV partials ----------------
__global__ __launch_bounds__(256) void k_pool1(
    const float* __restrict__ x64, const float* __restrict__ pw,
    float* __restrict__ pacc) {
  __shared__ float pws[48][256];
  __shared__ float xs[16][48];
  int i0 = blockIdx.x * 48, j0 = blockIdx.y * 256, b0 = blockIdx.z * 16;
  for (int r = 0; r < 48; r++) pws[r][threadIdx.x] = pw[(long)(i0 + r) * cD + j0 + threadIdx.x];
  for (int idx = threadIdx.x; idx < 16 * 48; idx += 256)
    xs[idx / 48][idx % 48] = x64[(long)(b0 + idx / 48) * cD + i0 + idx % 48];
  __syncthreads();
  int j = threadIdx.x;
  for (int b = 0; b < 16; b++) {
    float acc = 0.f;
#pragma unroll 8
    for (int i = 0; i < 48; i++) acc += xs[b][i] * pws[i][j];
    atomicAdd(&pacc[(long)(b0 + b) * cD + j0 + j], acc);
  }
}
__global__ __launch_bounds__(256) void k_pool2(
    const float* __restrict__ pacc, const float* __restrict__ pb,
    float* __restrict__ pooled) {
  int b = blockIdx.x;
#pragma unroll
  for (int c = 0; c < 3; c++) {
    int j = (c << 8) + threadIdx.x;
    pooled[(long)b * cD + j] = tanhf(pacc[(long)b * cD + j] + pb[j]);
  }
}

// ---------------- dep LUT ----------------
__global__ __launch_bounds__(256) void k_s45(
    const float* __restrict__ dep_emb, const float* __restrict__ fc1w,
    const float* __restrict__ fc1b, const float* __restrict__ fc2w,
    const float* __restrict__ fc2b, float* __restrict__ s45) {
  int t = blockIdx.x;
  __shared__ float e[300];
  for (int i = threadIdx.x; i < 300; i += 256) e[i] = dep_emb[t * 300 + i];
  __syncthreads();
  int j = threadIdx.x;
  float h = fc1b[j];
  for (int i = 0; i < 300; i++) h += e[i] * fc1w[i * 256 + j];
  h = fmaxf(h, 0.f);
  float tot = blockSum(h * fc2w[j]);
  if (threadIdx.x == 0) s45[t] = tot + fc2b[0];
}

__global__ __launch_bounds__(256) void k_depfeat(
    const int* __restrict__ ori, const float* __restrict__ src_mask,
    const float* __restrict__ s45, float* __restrict__ dep_feat) {
  int b = blockIdx.x, l = threadIdx.x;
  float smv = (l == 0) ? 1.f : src_mask[b * cL + l];
  float sc = s45[ori[b * cL + l]] * smv + (1.f - smv) * (-1e30f);
  float mx = blockMax(sc);
  float ex = expf(sc - mx);
  float sum = blockSum(ex);
  dep_feat[b * cL + l] = ex / sum;
}

// ---------------- bias concat for fused projection ----------------
__global__ void k_bcat(const float* __restrict__ a, const float* __restrict__ b,
                       const float* __restrict__ c, const float* __restrict__ d,
                       float* __restrict__ o) {
  int i = blockIdx.x * 256 + threadIdx.x;
  float v = (i < 768) ? a[i] : (i < 1536) ? b[i - 768] : (i < 2304) ? c[i - 1536] : d[i - 2304];
  o[i] = v;
}

// ---------------- adj_ag softmax (bf16 scores in) ----------------
__global__ __launch_bounds__(256) void k_adjag_sm(
    const __hip_bfloat16* __restrict__ scores, const float* __restrict__ src_mask,
    __hip_bfloat16* __restrict__ adjag) {
  int b = blockIdx.x >> 8, i = blockIdx.x & 255;
  int tid = threadIdx.x, wave = tid >> 6, lane = tid & 63;
  __shared__ float accs[4][256];
  const float scale = 1.f / (sqrtf(96.f) + 1e-9f);
  float smj[4], acc[4];
#pragma unroll
  for (int c = 0; c < 4; c++) {
    int j = c * 64 + lane;
    smj[c] = (j == 0) ? 1.f : src_mask[b * cL + j];
    acc[c] = 0.f;
  }
  for (int hh = 0; hh < 2; hh++) {
    int h = wave * 2 + hh;
    const __hip_bfloat16* row = scores + (((long)(b * 8 + h)) * cL + i) * cL;
    float s[4], m = -1e30f;
#pragma unroll
    for (int c = 0; c < 4; c++) {
      s[c] = (smj[c] == 0.f) ? -1e9f : __bfloat162float(row[c * 64 + lane]) * scale;
      m = fmaxf(m, s[c]);
    }
    m = wmax_all(m);
    float es = 0.f;
#pragma unroll
    for (int c = 0; c < 4; c++) { s[c] = expf(s[c] - m); es += s[c]; }
    es = wsum_all(es);
    float inv = 1.f / es;
#pragma unroll
    for (int c = 0; c < 4; c++) acc[c] += s[c] * inv;
  }
#pragma unroll
  for (int c = 0; c < 4; c++) accs[wave][c * 64 + lane] = acc[c];
  __syncthreads();
  int j = tid;
  float tot = accs[0][j] + accs[1][j] + accs[2][j] + accs[3][j];
  float smi = (i == 0) ? 1.f : src_mask[b * cL + i];
  float v = (j == i) ? 1.f : tot * 0.125f;
  adjag[((long)b * cL + i) * cL + j] = __float2bfloat16(v * smi);
}

// ---------------- adj_latent softmax with inlined dep_adj ----------------
// dep_adj[i,j]: scatter1 sets (head[jj], jj+1)=df[jj]; scatter2 (applied after,
// wins) sets (jj+1, head[jj])=df[jj].  Per-cell closed form below.
__global__ __launch_bounds__(256) void k_adjlat_sm(
    const __hip_bfloat16* __restrict__ latsc, const int* __restrict__ head,
    const float* __restrict__ df, const float* __restrict__ src_mask,
    __hip_bfloat16* __restrict__ adjlat) {
  int b = blockIdx.x >> 8, i = blockIdx.x & 255;
  int j = threadIdx.x;
  float smj = (j == 0) ? 1.f : src_mask[b * cL + j];
  float dep = 1.f;
  if (j >= 1 && head[b * cL + j - 1] == i) dep = df[b * cL + j - 1];
  if (i >= 1 && j == head[b * cL + i - 1]) dep = df[b * cL + i - 1];
  float s = __bfloat162float(latsc[((long)b * cL + i) * cL + j]) * (1.f / sqrtf(768.f)) +
            dep + (1.f - smj) * (-10000.f);
  float mx = blockMax(s);
  float ex = expf(s - mx);
  float sum = blockSum(ex);
  float p = ex / sum;
  float smi = (i == 0) ? 1.f : src_mask[b * cL + i];
  adjlat[((long)b * cL + i) * cL + j] = __float2bfloat16(((j == i) ? 1.f : p) * smi);
}

// ---------------- wave-per-row dot ----------------
__global__ __launch_bounds__(256) void k_rowdot(
    const float* __restrict__ X, const float* __restrict__ w, long wstride,
    float* __restrict__ e) {
  int r = blockIdx.x * 4 + (threadIdx.x >> 6);
  int lane = threadIdx.x & 63;
  const float4* row = (const float4*)(X + (long)r * cD);
  const float4* wp = (const float4*)(w + (long)(r >> 8) * wstride);
  float s = 0.f;
#pragma unroll
  for (int c = 0; c < 3; c++) {
    int idx = c * 64 + lane;
    float4 a = row[idx], b = wp[idx];
    s += a.x * b.x + a.y * b.y + a.z * b.z + a.w * b.w;
  }
  s = wsum(s);
  if (lane == 0) e[r] = s;
}

// ---------------- root loss ----------------
__global__ __launch_bounds__(256) void k_root2(
    const float* __restrict__ e1, const float* __restrict__ src_mask,
    const float* __restrict__ aspect_mask, float* __restrict__ out_loss) {
  int b = blockIdx.x, l = threadIdx.x;
  float r = e1[b * cL + l];
  float smv = (l == 0) ? 1.f : src_mask[b * cL + l];
  float sc = r * smv + (1.f - smv) * (-1e30f);
  float mx = blockMax(sc);
  float ex = expf(sc - mx);
  float sum = blockSum(ex);
  float p = ex / sum;
  float tot = blockSum(p * aspect_mask[b * cL + l]);
  if (l == 0) atomicAdd(out_loss, -logf(tot + 1e-9f) * (1.f / 64.f));
}

// ---------------- lexicon loss ----------------
__global__ __launch_bounds__(256) void k_lex2(
    const float* __restrict__ e2, const float* __restrict__ src_mask,
    const float* __restrict__ lex, float* __restrict__ out_loss) {
  int b = blockIdx.x, l = threadIdx.x;
  float e = e2[b * cL + l];
  float mx = blockMax(e);
  float ex = expf(e - mx);
  float sum = blockSum(ex);
  float mult = (l == 0) ? 0.f : src_mask[b * cL + l];
  float lw = ex / sum * 50.f * mult;
  float d2 = lw - lex[b * cL + l];
  float tot = blockSum(d2 * d2);
  if (l == 0) atomicAdd(out_loss, tot * (1.f / (64.f * 256.f)));
}

// ---------------- hlsum partials ----------------
__global__ __launch_bounds__(256) void k_hl(
    const float* __restrict__ H, const float* __restrict__ src_mask,
    float* __restrict__ hlsum) {
  int b = blockIdx.z, d = (blockIdx.y << 8) + threadIdx.x, l0 = blockIdx.x * 32;
  float acc = 0.f;
  for (int l = l0; l < l0 + 32; l++) {
    float smv = (l == 0) ? 1.f : src_mask[b * cL + l];
    acc += H[((long)b * cL + l) * cD + d] * smv;
  }
  atomicAdd(&hlsum[(long)b * cD + d], acc);
}

// ---------------- attn weights + asum ----------------
__global__ __launch_bounds__(256) void k_attnw(
    const float* __restrict__ sraw, const float* __restrict__ src_mask,
    const float* __restrict__ am, float* __restrict__ wgt, float* __restrict__ asum) {
  int b = blockIdx.x, k = threadIdx.x;
  float smk = (k == 0) ? 1.f : src_mask[b * cL + k];
  float s = sraw[b * cL + k] * smk * 0.001f;
  float mx = blockMax(s);
  float ex = expf(s - mx);
  float sum = blockSum(ex);
  wgt[b * cL + k] = ex / sum;
  float a = blockSum(am[b * cL + k]);
  if (k == 0) asum[b] = a;
}

// ---------------- fused outputs+sempool partials ----------------
__global__ __launch_bounds__(256) void k_wsum(
    const float* __restrict__ Isem, const float* __restrict__ wgt,
    const float* __restrict__ am, float* __restrict__ outputs,
    float* __restrict__ sempool) {
  int b = blockIdx.z, d = (blockIdx.y << 8) + threadIdx.x, l0 = blockIdx.x * 32;
  float accO = 0.f, accS = 0.f;
  for (int l = l0; l < l0 + 32; l++) {
    float v = Isem[((long)b * cL + l) * cD + d];
    accO += wgt[b * cL + l] * v;
    accS += am[b * cL + l] * v;
  }
  atomicAdd(&outputs[(long)b * cD + d], accO);
  atomicAdd(&sempool[(long)b * cD + d], accS);
}

// ---------------- logits ----------------
__global__ __launch_bounds__(256) void k_logits(
    const float* __restrict__ outputs, const float* __restrict__ sempool,
    const float* __restrict__ pooled, const float* __restrict__ asum,
    const float* __restrict__ cw, const float* __restrict__ cb,
    float* __restrict__ out) {
  int b = blockIdx.x;
  float inv = 1.f / (asum[b] + 1e-9f);
  float a0 = 0.f, a1 = 0.f, a2 = 0.f;
  for (int i = threadIdx.x; i < 3 * cD; i += 256) {
    float f = (i < cD) ? outputs[(long)b * cD + i]
              : (i < 2 * cD) ? sempool[(long)b * cD + i - cD] * inv
                             : pooled[(long)b * cD + i - 2 * cD];
    a0 += f * cw[i * 3 + 0];
    a1 += f * cw[i * 3 + 1];
    a2 += f * cw[i * 3 + 2];
  }
  a0 = blockSum(a0);
  a1 = blockSum(a1);
  a2 = blockSum(a2);
  if (threadIdx.x == 0) {
    out[b * 3 + 0] = a0 + cb[0];
    out[b * 3 + 1] = a1 + cb[1];
    out[b * 3 + 2] = a2 + cb[2];
  }
}

extern "C" void kernel_launch(void* const* d_in, const int* in_sizes, int n_in,
                              void* d_out, int out_size, void* d_ws, size_t ws_size,
                              hipStream_t stream) {
  const int* tbi = (const int*)d_in[0];
  const int* bsi = (const int*)d_in[1];
  const float* src_mask = (const float*)d_in[3];
  const float* aspect_mask = (const float*)d_in[4];
  const float* lex = (const float*)d_in[5];
  const int* ori = (const int*)d_in[6];
  const int* head = (const int*)d_in[7];
  const float* tok_emb = (const float*)d_in[8];
  const float* seg_emb = (const float*)d_in[9];
  const float* pool_w = (const float*)d_in[10];
  const float* pool_b = (const float*)d_in[11];
  const float* ln_a = (const float*)d_in[12];
  const float* ln_b = (const float*)d_in[13];
  const float* dep_emb = (const float*)d_in[14];
  const float* fc1_w = (const float*)d_in[15];
  const float* fc1_b = (const float*)d_in[16];
  const float* fc2_w = (const float*)d_in[17];
  const float* fc2_b = (const float*)d_in[18];
  const float* aq_w = (const float*)d_in[19];
  const float* aq_b = (const float*)d_in[20];
  const float* ak_w = (const float*)d_in[21];
  const float* ak_b = (const float*)d_in[22];
  const float* lq_w = (const float*)d_in[23];
  const float* lq_b = (const float*)d_in[24];
  const float* lk_w = (const float*)d_in[25];
  const float* lk_b = (const float*)d_in[26];
  const float* root_w = (const float*)d_in[27];
  const float* gcn_w = (const float*)d_in[28];
  const float* gcn_b = (const float*)d_in[29];
  const float* fc3_w = (const float*)d_in[30];
  const float* fc3_b = (const float*)d_in[31];
  const float* cls_w = (const float*)d_in[32];
  const float* cls_b = (const float*)d_in[33];
  const float* vlin_w = (const float*)d_in[34];

  float* out = (float*)d_out;
  float* ws = (float*)d_ws;
  // fp32 region (~102 MB)
  float* gcnH = ws;            // BLD (gcn_in -> H_l)
  float* Isem = gcnH + BLD;    // BLD
  float* depfeat = Isem + BLD;         // B*L
  float* s45 = depfeat + cB * cL;      // 64
  float* pooled = s45 + 64;            // B*D
  float* x64 = pooled + cB * cD;       // B*D
  float* hlsum = x64 + cB * cD;        // B*D  --- zeroed region start
  float* outputs = hlsum + cB * cD;    // B*D
  float* sempool = outputs + cB * cD;  // B*D
  float* pacc = sempool + cB * cD;     // B*D  --- zeroed region end
  float* e1 = pacc + cB * cD;          // B*L
  float* e2 = e1 + cB * cL;            // B*L
  float* sraw = e2 + cB * cL;          // B*L
  float* wgt = sraw + cB * cL;         // B*L
  float* asum = wgt + cB * cL;         // 64
  float* catb = asum + 64;             // 3072
  // bf16 region (~218 MB)
  __hip_bfloat16* gib = (__hip_bfloat16*)(catb + 3072);  // BLD
  __hip_bfloat16* qkb = gib + BLD;           // 4*BLD (q|k|q2|k2, ldc=3072)
  __hip_bfloat16* scores = qkb + 4 * BLD;    // 8*BLL
  __hip_bfloat16* adjag_b = scores + 8 * BLL;  // BLL
  __hip_bfloat16* adjlat_b = adjag_b + BLL;    // BLL
  __hip_bfloat16* wbt = adjlat_b + BLL;        // 7*D*D
  // aliases
  __hip_bfloat16* latsc_b = scores;        // BLL (scores dead by then)
  __hip_bfloat16* HWb = qkb;               // BLD
  __hip_bfloat16* HWbT = qkb + BLD;        // BLD
  __hip_bfloat16* Icb = qkb + 2 * BLD;     // BLD

  hipMemsetAsync((char*)d_out + 192 * sizeof(float), 0, 2 * sizeof(float), stream);
  hipMemsetAsync(hlsum, 0, 4 * cB * cD * sizeof(float), stream);

  // ---- prologue ----
  k_gcnin<<<cB * cL, 256, 0, stream>>>(tbi, bsi, tok_emb, seg_emb, ln_a, ln_b, gcnH, gib, x64);
  k_s45<<<45, 256, 0, stream>>>(dep_emb, fc1_w, fc1_b, fc2_w, fc2_b, s45);
  k_depfeat<<<cB, 256, 0, stream>>>(ori, src_mask, s45, depfeat);
  k_pool1<<<dim3(16, 3, 4), 256, 0, stream>>>(x64, pool_w, pacc);
  k_pool2<<<cB, 256, 0, stream>>>(pacc, pool_b, pooled);
  k_bcat<<<12, 256, 0, stream>>>(aq_b, ak_b, lq_b, lk_b, catb);

  // ---- weights -> bf16 transposed (N x K); proj weights contiguous ----
  dim3 gw(24, 24), bw(32, 8);
  const long DD = (long)cD * cD;
  k_wconv<<<gw, bw, 0, stream>>>(aq_w, wbt + 0 * DD);
  k_wconv<<<gw, bw, 0, stream>>>(ak_w, wbt + 1 * DD);
  k_wconv<<<gw, bw, 0, stream>>>(lq_w, wbt + 2 * DD);
  k_wconv<<<gw, bw, 0, stream>>>(lk_w, wbt + 3 * DD);
  k_wconv<<<gw, bw, 0, stream>>>(gcn_w, wbt + 4 * DD);
  k_wconv<<<gw, bw, 0, stream>>>(gcn_w + DD, wbt + 5 * DD);
  k_wconv<<<gw, bw, 0, stream>>>(fc3_w, wbt + 6 * DD);

  const long LD = (long)cL * cD, LL = (long)cL * cL;
  const long LP = (long)cL * 3072;  // qkb batch stride

  // ---- fused 4-way projection: qkb = gib @ [aq|ak|lq|lk] + catb ----
  bgemm<1, 0, 1, 0><<<dim3(24, 128, 1), 256, 0, stream>>>(
      gib, wbt, qkb, catb, nullptr, nullptr, cD, cD, cD, 3072, 0, 0, 0, 0, 0, 0, 0);

  // ---- head scores (bf16 out) + adj_ag softmax ----
  bgemm<1, 0, 0, 0><<<dim3(2, 2, cB * 8), 256, 0, stream>>>(
      qkb, qkb + 768, scores, nullptr, nullptr, nullptr,
      96, 3072, 3072, cL, 3, 7, LP, 96, LP, 96, LL);
  k_adjag_sm<<<cB * cL, 256, 0, stream>>>(scores, src_mask, adjag_b);

  // ---- latent scores (bf16 out, aliases scores) + adj_latent softmax ----
  bgemm<1, 0, 0, 0><<<dim3(2, 2, cB), 256, 0, stream>>>(
      qkb + 1536, qkb + 2304, latsc_b, nullptr, nullptr, nullptr,
      cD, 3072, 3072, cL, 0, 0, LP, 0, LP, 0, LL);
  k_adjlat_sm<<<cB * cL, 256, 0, stream>>>(latsc_b, head, depfeat, src_mask, adjlat_b);

  // ---- root loss (gcnH still == gcn_in here) ----
  k_rowdot<<<cB * cL / 4, 256, 0, stream>>>(gcnH, root_w, 0, e1);
  k_root2<<<cB, 256, 0, stream>>>(e1, src_mask, aspect_mask, out + 192);

  // ---- GCN loop ----
  dim3 gBig(6, 128, 1), gAdj(6, 2, cB);
  dim3 gt(cL / 32, cD / 32, cB), bt(32, 8);
  for (int layer = 0; layer < 2; layer++) {
    const float* bb = gcn_b + (long)layer * cD;
    // HW = H @ W (bf16)
    bgemm<1, 0, 0, 0><<<gBig, 256, 0, stream>>>(
        gib, wbt + (4 + layer) * DD, HWb, nullptr, nullptr, nullptr,
        cD, cD, cD, cD, 0, 0, 0, 0, 0, 0, 0);
    k_tbf16<<<gt, bt, 0, stream>>>(HWb, HWbT);
    // Isem = adjag @ HW + b (f32)
    bgemm<0, 0, 1, 0><<<gAdj, 256, 0, stream>>>(
        adjag_b, HWbT, Isem, bb, nullptr, nullptr,
        cL, cL, cL, cD, 0, 0, LL, 0, LD, 0, LD);
    // Ilat GEMM with fused I_com epilogue -> Icb (bf16)
    bgemm<0, 0, 1, 1><<<gAdj, 256, 0, stream>>>(
        adjlat_b, HWbT, nullptr, bb, Isem, Icb,
        cL, cL, cL, cD, 0, 0, LL, 0, LD, 0, LD);
    // fc3 GEMM with fused H-gate epilogue: updates gcnH (f32) + gib (bf16)
    bgemm<0, 1, 1, 2><<<gBig, 256, 0, stream>>>(
        Icb, wbt + 6 * DD, nullptr, fc3_b, gcnH, gib,
        cD, cD, cD, cD, 0, 0, 0, 0, 0, 0, 0);
  }

  // ---- tail ----
  k_hl<<<dim3(8, 3, cB), 256, 0, stream>>>(gcnH, src_mask, hlsum);
  k_rowdot<<<cB * cL / 4, 256, 0, stream>>>(Isem, hlsum, cD, sraw);
  k_attnw<<<cB, 256, 0, stream>>>(sraw, src_mask, aspect_mask, wgt, asum);
  k_wsum<<<dim3(8, 3, cB), 256, 0, stream>>>(Isem, wgt, aspect_mask, outputs, sempool);
  k_logits<<<cB, 256, 0, stream>>>(outputs, sempool, pooled, asum, cls_w, cls_b, out);
  k_rowdot<<<cB * cL / 4, 256, 0, stream>>>(gcnH, vlin_w, 0, e2);
  k_lex2<<<cB, 256, 0, stream>>>(e2, src_mask, lex, out + 193);
}

// Round 5
// 919.940 us; speedup vs baseline: 1.1696x; 1.1696x over previous
//
#include <hip/hip_runtime.h>
#include <hip/hip_bf16.h>
#include <math.h>

#define DI __device__ __forceinline__

constexpr int cB = 64, cL = 256, cD = 768;
constexpr long BLD = (long)cB * cL * cD;   // 12,582,912
constexpr long BLL = (long)cB * cL * cL;   //  4,194,304

typedef __attribute__((ext_vector_type(8))) short b8;
typedef __attribute__((ext_vector_type(4))) float f4;

// ---------------- reductions (wave64) ----------------
DI float wsum(float v) {
#pragma unroll
  for (int o = 32; o > 0; o >>= 1) v += __shfl_down(v, o, 64);
  return v;
}
DI float wsum_all(float v) {
#pragma unroll
  for (int m = 32; m > 0; m >>= 1) v += __shfl_xor(v, m, 64);
  return v;
}
DI float wmax_all(float v) {
#pragma unroll
  for (int m = 32; m > 0; m >>= 1) v = fmaxf(v, __shfl_xor(v, m, 64));
  return v;
}
DI float wmaxr(float v) {
#pragma unroll
  for (int o = 32; o > 0; o >>= 1) v = fmaxf(v, __shfl_down(v, o, 64));
  return v;
}
DI float blockSum(float v) {
  __shared__ float sh[4];
  v = wsum(v);
  __syncthreads();
  if ((threadIdx.x & 63) == 0) sh[threadIdx.x >> 6] = v;
  __syncthreads();
  return sh[0] + sh[1] + sh[2] + sh[3];
}
DI float blockMax(float v) {
  __shared__ float sh[4];
  v = wmaxr(v);
  __syncthreads();
  if ((threadIdx.x & 63) == 0) sh[threadIdx.x >> 6] = v;
  __syncthreads();
  return fmaxf(fmaxf(sh[0], sh[1]), fmaxf(sh[2], sh[3]));
}
DI float sigf(float x) { return 1.f / (1.f + expf(-x)); }

// ================= bf16 MFMA GEMM: C = A(MxK) @ BT(NxK)^T =================
// 128x128 tile, 4 waves, 4x4 of 16x16x32 frags/wave, BK=32.
// Register-prefetch staging (round-3 proven): global loads for tile k+1
// issue right after the staging barrier and retire during the 32 MFMAs.
// LDS chunk layout slot(m,q) = q*129 + m (+1-chunk pad per q-block).
// EPI: 0=plain (OBF/RELU), 1=I_com (read auxf=Isem, write auxb bf16),
//      2=H-update (relu -> gate vs auxf=H in place, write auxb bf16).
template <int OBF, int RELU, int BIAS, int EPI>
__global__ __launch_bounds__(256, 2) void bgemm(
    const __hip_bfloat16* __restrict__ A, const __hip_bfloat16* __restrict__ BT,
    void* __restrict__ Cv, const float* __restrict__ bias,
    float* __restrict__ auxf, __hip_bfloat16* __restrict__ auxb,
    int K, int lda, int ldb, int ldc,
    int zshift, int zmask, long sA1, long sA2, long sB1, long sB2, long sC) {
  __shared__ __hip_bfloat16 Asp[4 * 129 * 8];
  __shared__ __hip_bfloat16 Bsp[4 * 129 * 8];
  int z = blockIdx.z;
  A += (long)(z >> zshift) * sA1 + (long)(z & zmask) * sA2;
  BT += (long)(z >> zshift) * sB1 + (long)(z & zmask) * sB2;
  int tid = threadIdx.x;
  int lane = tid & 63, w = tid >> 6;
  int wr = w >> 1, wc = w & 1;
  int l16 = lane & 15, q = lane >> 4;
  int m0 = blockIdx.y << 7, n0 = blockIdx.x << 7;

  int fm = tid >> 2, fq = tid & 3;  // staging chunk (row, k-chunk); +64 -> row+64
  const __hip_bfloat16* Ap0 = A + (long)(m0 + fm) * lda + fq * 8;
  const __hip_bfloat16* Ap1 = A + (long)(m0 + fm + 64) * lda + fq * 8;
  const __hip_bfloat16* Bp0 = BT + (long)(n0 + fm) * ldb + fq * 8;
  const __hip_bfloat16* Bp1 = BT + (long)(n0 + fm + 64) * ldb + fq * 8;
  __hip_bfloat16* Aw0 = &Asp[(fq * 129 + fm) * 8];
  __hip_bfloat16* Aw1 = &Asp[(fq * 129 + fm + 64) * 8];
  __hip_bfloat16* Bw0 = &Bsp[(fq * 129 + fm) * 8];
  __hip_bfloat16* Bw1 = &Bsp[(fq * 129 + fm + 64) * 8];

  f4 acc[4][4];
#pragma unroll
  for (int i = 0; i < 4; i++)
#pragma unroll
    for (int j = 0; j < 4; j++) acc[i][j] = (f4){0.f, 0.f, 0.f, 0.f};

  b8 pa0 = *(const b8*)Ap0, pa1 = *(const b8*)Ap1;
  b8 pb0 = *(const b8*)Bp0, pb1 = *(const b8*)Bp1;
  for (int k0 = 0; k0 < K; k0 += 32) {
    __syncthreads();
    *(b8*)Aw0 = pa0; *(b8*)Aw1 = pa1;
    *(b8*)Bw0 = pb0; *(b8*)Bw1 = pb1;
    __syncthreads();
    int k1 = k0 + 32;
    if (k1 < K) {
      pa0 = *(const b8*)(Ap0 + k1); pa1 = *(const b8*)(Ap1 + k1);
      pb0 = *(const b8*)(Bp0 + k1); pb1 = *(const b8*)(Bp1 + k1);
    }
    b8 af[4], bf[4];
#pragma unroll
    for (int i = 0; i < 4; i++)
      af[i] = *(const b8*)&Asp[(q * 129 + wr * 64 + i * 16 + l16) * 8];
#pragma unroll
    for (int j = 0; j < 4; j++)
      bf[j] = *(const b8*)&Bsp[(q * 129 + wc * 64 + j * 16 + l16) * 8];
#pragma unroll
    for (int i = 0; i < 4; i++)
#pragma unroll
      for (int j = 0; j < 4; j++)
        acc[i][j] = __builtin_amdgcn_mfma_f32_16x16x32_bf16(af[i], bf[j], acc[i][j], 0, 0, 0);
  }
  long cz = (long)z * sC;
#pragma unroll
  for (int j = 0; j < 4; j++) {
    int n = n0 + wc * 64 + j * 16 + l16;
    float bv = BIAS ? bias[n] : 0.f;
#pragma unroll
    for (int i = 0; i < 4; i++) {
#pragma unroll
      for (int r = 0; r < 4; r++) {
        int m = m0 + wr * 64 + i * 16 + q * 4 + r;
        long idx = cz + (long)m * ldc + n;
        float v = acc[i][j][r] + bv;
        if (EPI == 0) {
          if (RELU) v = fmaxf(v, 0.f);
          if (OBF)
            ((__hip_bfloat16*)Cv)[idx] = __float2bfloat16(v);
          else
            ((float*)Cv)[idx] = v;
        } else if (EPI == 1) {
          // v = I_lat; I_com = Isem + 0.5*sig(v)*(v - Isem)
          float is = auxf[idx];
          float g = 0.5f * sigf(v);
          auxb[idx] = __float2bfloat16(is + g * (v - is));
        } else {
          // v = Hout = relu(acc+bias); H' = H + sig(H)*(Hout - H)
          v = fmaxf(v, 0.f);
          float h = auxf[idx];
          float g = sigf(h);
          float o = h + g * (v - h);
          auxf[idx] = o;
          auxb[idx] = __float2bfloat16(o);
        }
      }
    }
  }
}

// ---------------- weight convert+transpose: dst[n*768+k] = bf16(src[k*768+n]) ----------------
__global__ void k_wconv(const float* __restrict__ src, __hip_bfloat16* __restrict__ dst) {
  __shared__ float t[32][33];
  int k0 = blockIdx.x * 32, n0 = blockIdx.y * 32;
  int tx = threadIdx.x, ty = threadIdx.y;
#pragma unroll
  for (int i = 0; i < 32; i += 8) t[ty + i][tx] = src[(long)(k0 + ty + i) * cD + n0 + tx];
  __syncthreads();
#pragma unroll
  for (int i = 0; i < 32; i += 8)
    dst[(long)(n0 + ty + i) * cD + k0 + tx] = __float2bfloat16(t[tx][ty + i]);
}

// ---------------- bf16 per-batch transpose: (B,L,D) -> (B,D,L) ----------------
__global__ void k_tbf16(const __hip_bfloat16* __restrict__ in, __hip_bfloat16* __restrict__ out) {
  __shared__ __hip_bfloat16 t[32][33];
  int b = blockIdx.z;
  int l0 = blockIdx.x * 32, d0 = blockIdx.y * 32;
  int tx = threadIdx.x, ty = threadIdx.y;
  const __hip_bfloat16* ip = in + (long)b * cL * cD;
  __hip_bfloat16* op = out + (long)b * cL * cD;
#pragma unroll
  for (int i = 0; i < 32; i += 8) t[ty + i][tx] = ip[(long)(l0 + ty + i) * cD + d0 + tx];
  __syncthreads();
#pragma unroll
  for (int i = 0; i < 32; i += 8) op[(long)(d0 + ty + i) * cL + l0 + tx] = t[tx][ty + i];
}

// ---------------- embedding + layernorm; also writes pre-LN x for l==0 ----------------
__global__ __launch_bounds__(256) void k_gcnin(
    const int* __restrict__ tbi, const int* __restrict__ bsi,
    const float* __restrict__ tok, const float* __restrict__ seg,
    const float* __restrict__ ln_a, const float* __restrict__ ln_b,
    float* __restrict__ gcn_in, __hip_bfloat16* __restrict__ gib,
    float* __restrict__ x64) {
  long bl = blockIdx.x;
  int t = tbi[bl], s = bsi[bl];
  const float* tr = tok + (long)t * cD;
  const float* sr = seg + (long)s * cD;
  float x[3];
  float ls = 0.f;
#pragma unroll
  for (int i = 0; i < 3; i++) {
    int d = threadIdx.x + (i << 8);
    x[i] = tr[d] + sr[d];
    ls += x[i];
  }
  if ((bl & 255) == 0) {
#pragma unroll
    for (int i = 0; i < 3; i++) x64[(bl >> 8) * cD + threadIdx.x + (i << 8)] = x[i];
  }
  float mean = blockSum(ls) * (1.f / 768.f);
  float lv = 0.f;
#pragma unroll
  for (int i = 0; i < 3; i++) { float c = x[i] - mean; lv += c * c; }
  float var = blockSum(lv) * (1.f / 767.f);
  float inv = 1.f / (sqrtf(var) + 1e-6f);
#pragma unroll
  for (int i = 0; i < 3; i++) {
    int d = threadIdx.x + (i << 8);
    float v = ln_a[d] * (x[i] - mean) * inv + ln_b[d];
    gcn_in[bl * cD + d] = v;
    gib[bl * cD + d] = __float2bfloat16(v);
  }
}

// ---------------- pooled GEMV partials ----------------
__global__ __launch_bounds__(256) void k_pool1(
    const float* __restrict__ x64, const float* __restrict__ pw,
    float* __restrict__ pacc) {
  __shared__ float pws[48][256];
  __shared__ float xs[16][48];
  int i0 = blockIdx.x * 48, j0 = blockIdx.y * 256, b0 = blockIdx.z * 16;
  for (int r = 0; r < 48; r++) pws[r][threadIdx.x] = pw[(long)(i0 + r) * cD + j0 + threadIdx.x];
  for (int idx = threadIdx.x; idx < 16 * 48; idx += 256)
    xs[idx / 48][idx % 48] = x64[(long)(b0 + idx / 48) * cD + i0 + idx % 48];
  __syncthreads();
  int j = threadIdx.x;
  for (int b = 0; b < 16; b++) {
    float acc = 0.f;
#pragma unroll 8
    for (int i = 0; i < 48; i++) acc += xs[b][i] * pws[i][j];
    atomicAdd(&pacc[(long)(b0 + b) * cD + j0 + j], acc);
  }
}
__global__ __launch_bounds__(256) void k_pool2(
    const float* __restrict__ pacc, const float* __restrict__ pb,
    float* __restrict__ pooled) {
  int b = blockIdx.x;
#pragma unroll
  for (int c = 0; c < 3; c++) {
    int j = (c << 8) + threadIdx.x;
    pooled[(long)b * cD + j] = tanhf(pacc[(long)b * cD + j] + pb[j]);
  }
}

// ---------------- dep LUT ----------------
__global__ __launch_bounds__(256) void k_s45(
    const float* __restrict__ dep_emb, const float* __restrict__ fc1w,
    const float* __restrict__ fc1b, const float* __restrict__ fc2w,
    const float* __restrict__ fc2b, float* __restrict__ s45) {
  int t = blockIdx.x;
  __shared__ float e[300];
  for (int i = threadIdx.x; i < 300; i += 256) e[i] = dep_emb[t * 300 + i];
  __syncthreads();
  int j = threadIdx.x;
  float h = fc1b[j];
  for (int i = 0; i < 300; i++) h += e[i] * fc1w[i * 256 + j];
  h = fmaxf(h, 0.f);
  float tot = blockSum(h * fc2w[j]);
  if (threadIdx.x == 0) s45[t] = tot + fc2b[0];
}

__global__ __launch_bounds__(256) void k_depfeat(
    const int* __restrict__ ori, const float* __restrict__ src_mask,
    const float* __restrict__ s45, float* __restrict__ dep_feat) {
  int b = blockIdx.x, l = threadIdx.x;
  float smv = (l == 0) ? 1.f : src_mask[b * cL + l];
  float sc = s45[ori[b * cL + l]] * smv + (1.f - smv) * (-1e30f);
  float mx = blockMax(sc);
  float ex = expf(sc - mx);
  float sum = blockSum(ex);
  dep_feat[b * cL + l] = ex / sum;
}

// ---------------- bias concat for fused projection ----------------
__global__ void k_bcat(const float* __restrict__ a, const float* __restrict__ b,
                       const float* __restrict__ c, const float* __restrict__ d,
                       float* __restrict__ o) {
  int i = blockIdx.x * 256 + threadIdx.x;
  float v = (i < 768) ? a[i] : (i < 1536) ? b[i - 768] : (i < 2304) ? c[i - 1536] : d[i - 2304];
  o[i] = v;
}

// ---------------- adj_ag softmax (bf16 scores in) ----------------
__global__ __launch_bounds__(256) void k_adjag_sm(
    const __hip_bfloat16* __restrict__ scores, const float* __restrict__ src_mask,
    __hip_bfloat16* __restrict__ adjag) {
  int b = blockIdx.x >> 8, i = blockIdx.x & 255;
  int tid = threadIdx.x, wave = tid >> 6, lane = tid & 63;
  __shared__ float accs[4][256];
  const float scale = 1.f / (sqrtf(96.f) + 1e-9f);
  float smj[4], acc[4];
#pragma unroll
  for (int c = 0; c < 4; c++) {
    int j = c * 64 + lane;
    smj[c] = (j == 0) ? 1.f : src_mask[b * cL + j];
    acc[c] = 0.f;
  }
  for (int hh = 0; hh < 2; hh++) {
    int h = wave * 2 + hh;
    const __hip_bfloat16* row = scores + (((long)(b * 8 + h)) * cL + i) * cL;
    float s[4], m = -1e30f;
#pragma unroll
    for (int c = 0; c < 4; c++) {
      s[c] = (smj[c] == 0.f) ? -1e9f : __bfloat162float(row[c * 64 + lane]) * scale;
      m = fmaxf(m, s[c]);
    }
    m = wmax_all(m);
    float es = 0.f;
#pragma unroll
    for (int c = 0; c < 4; c++) { s[c] = expf(s[c] - m); es += s[c]; }
    es = wsum_all(es);
    float inv = 1.f / es;
#pragma unroll
    for (int c = 0; c < 4; c++) acc[c] += s[c] * inv;
  }
#pragma unroll
  for (int c = 0; c < 4; c++) accs[wave][c * 64 + lane] = acc[c];
  __syncthreads();
  int j = tid;
  float tot = accs[0][j] + accs[1][j] + accs[2][j] + accs[3][j];
  float smi = (i == 0) ? 1.f : src_mask[b * cL + i];
  float v = (j == i) ? 1.f : tot * 0.125f;
  adjag[((long)b * cL + i) * cL + j] = __float2bfloat16(v * smi);
}

// ---------------- adj_latent softmax with inlined dep_adj ----------------
// dep_adj[i,j]: scatter1 sets (head[jj], jj+1)=df[jj]; scatter2 (applied after,
// wins) sets (jj+1, head[jj])=df[jj].
__global__ __launch_bounds__(256) void k_adjlat_sm(
    const __hip_bfloat16* __restrict__ latsc, const int* __restrict__ head,
    const float* __restrict__ df, const float* __restrict__ src_mask,
    __hip_bfloat16* __restrict__ adjlat) {
  int b = blockIdx.x >> 8, i = blockIdx.x & 255;
  int j = threadIdx.x;
  float smj = (j == 0) ? 1.f : src_mask[b * cL + j];
  float dep = 1.f;
  if (j >= 1 && head[b * cL + j - 1] == i) dep = df[b * cL + j - 1];
  if (i >= 1 && j == head[b * cL + i - 1]) dep = df[b * cL + i - 1];
  float s = __bfloat162float(latsc[((long)b * cL + i) * cL + j]) * (1.f / sqrtf(768.f)) +
            dep + (1.f - smj) * (-10000.f);
  float mx = blockMax(s);
  float ex = expf(s - mx);
  float sum = blockSum(ex);
  float p = ex / sum;
  float smi = (i == 0) ? 1.f : src_mask[b * cL + i];
  adjlat[((long)b * cL + i) * cL + j] = __float2bfloat16(((j == i) ? 1.f : p) * smi);
}

// ---------------- wave-per-row dot ----------------
__global__ __launch_bounds__(256) void k_rowdot(
    const float* __restrict__ X, const float* __restrict__ w, long wstride,
    float* __restrict__ e) {
  int r = blockIdx.x * 4 + (threadIdx.x >> 6);
  int lane = threadIdx.x & 63;
  const float4* row = (const float4*)(X + (long)r * cD);
  const float4* wp = (const float4*)(w + (long)(r >> 8) * wstride);
  float s = 0.f;
#pragma unroll
  for (int c = 0; c < 3; c++) {
    int idx = c * 64 + lane;
    float4 a = row[idx], b = wp[idx];
    s += a.x * b.x + a.y * b.y + a.z * b.z + a.w * b.w;
  }
  s = wsum(s);
  if (lane == 0) e[r] = s;
}

// ---------------- root loss ----------------
__global__ __launch_bounds__(256) void k_root2(
    const float* __restrict__ e1, const float* __restrict__ src_mask,
    const float* __restrict__ aspect_mask, float* __restrict__ out_loss) {
  int b = blockIdx.x, l = threadIdx.x;
  float r = e1[b * cL + l];
  float smv = (l == 0) ? 1.f : src_mask[b * cL + l];
  float sc = r * smv + (1.f - smv) * (-1e30f);
  float mx = blockMax(sc);
  float ex = expf(sc - mx);
  float sum = blockSum(ex);
  float p = ex / sum;
  float tot = blockSum(p * aspect_mask[b * cL + l]);
  if (l == 0) atomicAdd(out_loss, -logf(tot + 1e-9f) * (1.f / 64.f));
}

// ---------------- lexicon loss ----------------
__global__ __launch_bounds__(256) void k_lex2(
    const float* __restrict__ e2, const float* __restrict__ src_mask,
    const float* __restrict__ lex, float* __restrict__ out_loss) {
  int b = blockIdx.x, l = threadIdx.x;
  float e = e2[b * cL + l];
  float mx = blockMax(e);
  float ex = expf(e - mx);
  float sum = blockSum(ex);
  float mult = (l == 0) ? 0.f : src_mask[b * cL + l];
  float lw = ex / sum * 50.f * mult;
  float d2 = lw - lex[b * cL + l];
  float tot = blockSum(d2 * d2);
  if (l == 0) atomicAdd(out_loss, tot * (1.f / (64.f * 256.f)));
}

// ---------------- hlsum partials ----------------
__global__ __launch_bounds__(256) void k_hl(
    const float* __restrict__ H, const float* __restrict__ src_mask,
    float* __restrict__ hlsum) {
  int b = blockIdx.z, d = (blockIdx.y << 8) + threadIdx.x, l0 = blockIdx.x * 32;
  float acc = 0.f;
  for (int l = l0; l < l0 + 32; l++) {
    float smv = (l == 0) ? 1.f : src_mask[b * cL + l];
    acc += H[((long)b * cL + l) * cD + d] * smv;
  }
  atomicAdd(&hlsum[(long)b * cD + d], acc);
}

// ---------------- attn weights + asum ----------------
__global__ __launch_bounds__(256) void k_attnw(
    const float* __restrict__ sraw, const float* __restrict__ src_mask,
    const float* __restrict__ am, float* __restrict__ wgt, float* __restrict__ asum) {
  int b = blockIdx.x, k = threadIdx.x;
  float smk = (k == 0) ? 1.f : src_mask[b * cL + k];
  float s = sraw[b * cL + k] * smk * 0.001f;
  float mx = blockMax(s);
  float ex = expf(s - mx);
  float sum = blockSum(ex);
  wgt[b * cL + k] = ex / sum;
  float a = blockSum(am[b * cL + k]);
  if (k == 0) asum[b] = a;
}

// ---------------- fused outputs+sempool partials ----------------
__global__ __launch_bounds__(256) void k_wsum(
    const float* __restrict__ Isem, const float* __restrict__ wgt,
    const float* __restrict__ am, float* __restrict__ outputs,
    float* __restrict__ sempool) {
  int b = blockIdx.z, d = (blockIdx.y << 8) + threadIdx.x, l0 = blockIdx.x * 32;
  float accO = 0.f, accS = 0.f;
  for (int l = l0; l < l0 + 32; l++) {
    float v = Isem[((long)b * cL + l) * cD + d];
    accO += wgt[b * cL + l] * v;
    accS += am[b * cL + l] * v;
  }
  atomicAdd(&outputs[(long)b * cD + d], accO);
  atomicAdd(&sempool[(long)b * cD + d], accS);
}

// ---------------- logits ----------------
__global__ __launch_bounds__(256) void k_logits(
    const float* __restrict__ outputs, const float* __restrict__ sempool,
    const float* __restrict__ pooled, const float* __restrict__ asum,
    const float* __restrict__ cw, const float* __restrict__ cb,
    float* __restrict__ out) {
  int b = blockIdx.x;
  float inv = 1.f / (asum[b] + 1e-9f);
  float a0 = 0.f, a1 = 0.f, a2 = 0.f;
  for (int i = threadIdx.x; i < 3 * cD; i += 256) {
    float f = (i < cD) ? outputs[(long)b * cD + i]
              : (i < 2 * cD) ? sempool[(long)b * cD + i - cD] * inv
                             : pooled[(long)b * cD + i - 2 * cD];
    a0 += f * cw[i * 3 + 0];
    a1 += f * cw[i * 3 + 1];
    a2 += f * cw[i * 3 + 2];
  }
  a0 = blockSum(a0);
  a1 = blockSum(a1);
  a2 = blockSum(a2);
  if (threadIdx.x == 0) {
    out[b * 3 + 0] = a0 + cb[0];
    out[b * 3 + 1] = a1 + cb[1];
    out[b * 3 + 2] = a2 + cb[2];
  }
}

extern "C" void kernel_launch(void* const* d_in, const int* in_sizes, int n_in,
                              void* d_out, int out_size, void* d_ws, size_t ws_size,
                              hipStream_t stream) {
  const int* tbi = (const int*)d_in[0];
  const int* bsi = (const int*)d_in[1];
  const float* src_mask = (const float*)d_in[3];
  const float* aspect_mask = (const float*)d_in[4];
  const float* lex = (const float*)d_in[5];
  const int* ori = (const int*)d_in[6];
  const int* head = (const int*)d_in[7];
  const float* tok_emb = (const float*)d_in[8];
  const float* seg_emb = (const float*)d_in[9];
  const float* pool_w = (const float*)d_in[10];
  const float* pool_b = (const float*)d_in[11];
  const float* ln_a = (const float*)d_in[12];
  const float* ln_b = (const float*)d_in[13];
  const float* dep_emb = (const float*)d_in[14];
  const float* fc1_w = (const float*)d_in[15];
  const float* fc1_b = (const float*)d_in[16];
  const float* fc2_w = (const float*)d_in[17];
  const float* fc2_b = (const float*)d_in[18];
  const float* aq_w = (const float*)d_in[19];
  const float* aq_b = (const float*)d_in[20];
  const float* ak_w = (const float*)d_in[21];
  const float* ak_b = (const float*)d_in[22];
  const float* lq_w = (const float*)d_in[23];
  const float* lq_b = (const float*)d_in[24];
  const float* lk_w = (const float*)d_in[25];
  const float* lk_b = (const float*)d_in[26];
  const float* root_w = (const float*)d_in[27];
  const float* gcn_w = (const float*)d_in[28];
  const float* gcn_b = (const float*)d_in[29];
  const float* fc3_w = (const float*)d_in[30];
  const float* fc3_b = (const float*)d_in[31];
  const float* cls_w = (const float*)d_in[32];
  const float* cls_b = (const float*)d_in[33];
  const float* vlin_w = (const float*)d_in[34];

  float* out = (float*)d_out;
  float* ws = (float*)d_ws;
  // fp32 region
  float* gcnH = ws;            // BLD (gcn_in -> H_l)
  float* Isem = gcnH + BLD;    // BLD
  float* depfeat = Isem + BLD;         // B*L
  float* s45 = depfeat + cB * cL;      // 64
  float* pooled = s45 + 64;            // B*D
  float* x64 = pooled + cB * cD;       // B*D
  float* hlsum = x64 + cB * cD;        // B*D  --- zeroed region start
  float* outputs = hlsum + cB * cD;    // B*D
  float* sempool = outputs + cB * cD;  // B*D
  float* pacc = sempool + cB * cD;     // B*D  --- zeroed region end
  float* e1 = pacc + cB * cD;          // B*L
  float* e2 = e1 + cB * cL;            // B*L
  float* sraw = e2 + cB * cL;          // B*L
  float* wgt = sraw + cB * cL;         // B*L
  float* asum = wgt + cB * cL;         // 64
  float* catb = asum + 64;             // 3072
  // bf16 region
  __hip_bfloat16* gib = (__hip_bfloat16*)(catb + 3072);  // BLD
  __hip_bfloat16* qkb = gib + BLD;             // 4*BLD (q|k|q2|k2, ldc=3072)
  __hip_bfloat16* scores = qkb + 4 * BLD;      // 8*BLL
  __hip_bfloat16* adjag_b = scores + 8 * BLL;  // BLL
  __hip_bfloat16* adjlat_b = adjag_b + BLL;    // BLL
  __hip_bfloat16* wbt = adjlat_b + BLL;        // 7*D*D
  // aliases
  __hip_bfloat16* latsc_b = scores;     // BLL (scores dead by then)
  __hip_bfloat16* HWb = qkb;            // BLD
  __hip_bfloat16* HWbT = qkb + BLD;     // BLD
  __hip_bfloat16* Icb = qkb + 2 * BLD;  // BLD

  hipMemsetAsync((char*)d_out + 192 * sizeof(float), 0, 2 * sizeof(float), stream);
  hipMemsetAsync(hlsum, 0, 4 * cB * cD * sizeof(float), stream);

  // ---- prologue ----
  k_gcnin<<<cB * cL, 256, 0, stream>>>(tbi, bsi, tok_emb, seg_emb, ln_a, ln_b, gcnH, gib, x64);
  k_s45<<<45, 256, 0, stream>>>(dep_emb, fc1_w, fc1_b, fc2_w, fc2_b, s45);
  k_depfeat<<<cB, 256, 0, stream>>>(ori, src_mask, s45, depfeat);
  k_pool1<<<dim3(16, 3, 4), 256, 0, stream>>>(x64, pool_w, pacc);
  k_pool2<<<cB, 256, 0, stream>>>(pacc, pool_b, pooled);
  k_bcat<<<12, 256, 0, stream>>>(aq_b, ak_b, lq_b, lk_b, catb);

  // ---- weights -> bf16 transposed (N x K); proj weights contiguous ----
  dim3 gw(24, 24), bw(32, 8);
  const long DD = (long)cD * cD;
  k_wconv<<<gw, bw, 0, stream>>>(aq_w, wbt + 0 * DD);
  k_wconv<<<gw, bw, 0, stream>>>(ak_w, wbt + 1 * DD);
  k_wconv<<<gw, bw, 0, stream>>>(lq_w, wbt + 2 * DD);
  k_wconv<<<gw, bw, 0, stream>>>(lk_w, wbt + 3 * DD);
  k_wconv<<<gw, bw, 0, stream>>>(gcn_w, wbt + 4 * DD);
  k_wconv<<<gw, bw, 0, stream>>>(gcn_w + DD, wbt + 5 * DD);
  k_wconv<<<gw, bw, 0, stream>>>(fc3_w, wbt + 6 * DD);

  const long LD = (long)cL * cD, LL = (long)cL * cL;
  const long LP = (long)cL * 3072;  // qkb batch stride

  // ---- fused 4-way projection: qkb = gib @ [aq|ak|lq|lk] + catb ----
  bgemm<1, 0, 1, 0><<<dim3(24, 128, 1), 256, 0, stream>>>(
      gib, wbt, qkb, catb, nullptr, nullptr, cD, cD, cD, 3072, 0, 0, 0, 0, 0, 0, 0);

  // ---- head scores (bf16 out) + adj_ag softmax ----
  bgemm<1, 0, 0, 0><<<dim3(2, 2, cB * 8), 256, 0, stream>>>(
      qkb, qkb + 768, scores, nullptr, nullptr, nullptr,
      96, 3072, 3072, cL, 3, 7, LP, 96, LP, 96, LL);
  k_adjag_sm<<<cB * cL, 256, 0, stream>>>(scores, src_mask, adjag_b);

  // ---- latent scores (bf16 out, aliases scores) + adj_latent softmax ----
  bgemm<1, 0, 0, 0><<<dim3(2, 2, cB), 256, 0, stream>>>(
      qkb + 1536, qkb + 2304, latsc_b, nullptr, nullptr, nullptr,
      cD, 3072, 3072, cL, 0, 0, LP, 0, LP, 0, LL);
  k_adjlat_sm<<<cB * cL, 256, 0, stream>>>(latsc_b, head, depfeat, src_mask, adjlat_b);

  // ---- root loss (gcnH still == gcn_in here) ----
  k_rowdot<<<cB * cL / 4, 256, 0, stream>>>(gcnH, root_w, 0, e1);
  k_root2<<<cB, 256, 0, stream>>>(e1, src_mask, aspect_mask, out + 192);

  // ---- GCN loop ----
  dim3 gBig(6, 128, 1), gAdj(6, 2, cB);
  dim3 gt(cL / 32, cD / 32, cB), bt(32, 8);
  for (int layer = 0; layer < 2; layer++) {
    const float* bb = gcn_b + (long)layer * cD;
    // HW = H @ W (bf16)
    bgemm<1, 0, 0, 0><<<gBig, 256, 0, stream>>>(
        gib, wbt + (4 + layer) * DD, HWb, nullptr, nullptr, nullptr,
        cD, cD, cD, cD, 0, 0, 0, 0, 0, 0, 0);
    k_tbf16<<<gt, bt, 0, stream>>>(HWb, HWbT);
    // Isem = adjag @ HW + b (f32)
    bgemm<0, 0, 1, 0><<<gAdj, 256, 0, stream>>>(
        adjag_b, HWbT, Isem, bb, nullptr, nullptr,
        cL, cL, cL, cD, 0, 0, LL, 0, LD, 0, LD);
    // Ilat GEMM with fused I_com epilogue -> Icb (bf16)
    bgemm<0, 0, 1, 1><<<gAdj, 256, 0, stream>>>(
        adjlat_b, HWbT, nullptr, bb, Isem, Icb,
        cL, cL, cL, cD, 0, 0, LL, 0, LD, 0, LD);
    // fc3 GEMM with fused H-gate epilogue: updates gcnH (f32) + gib (bf16)
    bgemm<0, 1, 1, 2><<<gBig, 256, 0, stream>>>(
        Icb, wbt + 6 * DD, nullptr, fc3_b, gcnH, gib,
        cD, cD, cD, cD, 0, 0, 0, 0, 0, 0, 0);
  }

  // ---- tail ----
  k_hl<<<dim3(8, 3, cB), 256, 0, stream>>>(gcnH, src_mask, hlsum);
  k_rowdot<<<cB * cL / 4, 256, 0, stream>>>(Isem, hlsum, cD, sraw);
  k_attnw<<<cB, 256, 0, stream>>>(sraw, src_mask, aspect_mask, wgt, asum);
  k_wsum<<<dim3(8, 3, cB), 256, 0, stream>>>(Isem, wgt, aspect_mask, outputs, sempool);
  k_logits<<<cB, 256, 0, stream>>>(outputs, sempool, pooled, asum, cls_w, cls_b, out);
  k_rowdot<<<cB * cL / 4, 256, 0, stream>>>(gcnH, vlin_w, 0, e2);
  k_lex2<<<cB, 256, 0, stream>>>(e2, src_mask, lex, out + 193);
}

// Round 6
// 899.103 us; speedup vs baseline: 1.1967x; 1.0232x over previous
//
#include <hip/hip_runtime.h>
#include <hip/hip_bf16.h>
#include <math.h>

#define DI __device__ __forceinline__

constexpr int cB = 64, cL = 256, cD = 768;
constexpr long BLD = (long)cB * cL * cD;   // 12,582,912
constexpr long BLL = (long)cB * cL * cL;   //  4,194,304
constexpr long cLL = (long)cL * cL;
constexpr long cLD = (long)cL * cD;

typedef __attribute__((ext_vector_type(8))) short b8;
typedef __attribute__((ext_vector_type(4))) float f4;

// ---------------- reductions (wave64) ----------------
DI float wsum(float v) {
#pragma unroll
  for (int o = 32; o > 0; o >>= 1) v += __shfl_down(v, o, 64);
  return v;
}
DI float wsum_all(float v) {
#pragma unroll
  for (int m = 32; m > 0; m >>= 1) v += __shfl_xor(v, m, 64);
  return v;
}
DI float wmax_all(float v) {
#pragma unroll
  for (int m = 32; m > 0; m >>= 1) v = fmaxf(v, __shfl_xor(v, m, 64));
  return v;
}
DI float wmaxr(float v) {
#pragma unroll
  for (int o = 32; o > 0; o >>= 1) v = fmaxf(v, __shfl_down(v, o, 64));
  return v;
}
DI float blockSum(float v) {
  __shared__ float sh[4];
  v = wsum(v);
  __syncthreads();
  if ((threadIdx.x & 63) == 0) sh[threadIdx.x >> 6] = v;
  __syncthreads();
  return sh[0] + sh[1] + sh[2] + sh[3];
}
DI float blockMax(float v) {
  __shared__ float sh[4];
  v = wmaxr(v);
  __syncthreads();
  if ((threadIdx.x & 63) == 0) sh[threadIdx.x >> 6] = v;
  __syncthreads();
  return fmaxf(fmaxf(sh[0], sh[1]), fmaxf(sh[2], sh[3]));
}
DI float sigf(float x) { return 1.f / (1.f + expf(-x)); }

// ================= bf16 MFMA GEMM: C = A(MxK) @ BT(NxK)^T =================
// 128x128 tile, 4 waves, 4x4 of 16x16x32 frags/wave, BK=32, register-prefetch.
// EPI: 0=plain (OBF/RELU), 2=H-update (relu -> gate vs auxf=H, write auxb bf16),
//      3=split-K f32 atomicAdd, 4=transposed bf16 write (per-256-row batch).
template <int OBF, int RELU, int BIAS, int EPI>
__global__ __launch_bounds__(256, 2) void bgemm(
    const __hip_bfloat16* __restrict__ A, const __hip_bfloat16* __restrict__ BT,
    void* __restrict__ Cv, const float* __restrict__ bias,
    float* __restrict__ auxf, __hip_bfloat16* __restrict__ auxb,
    int K, int lda, int ldb, int ldc,
    int zshift, int zmask, long sA1, long sA2, long sB1, long sB2, long sC,
    int czdiv) {
  __shared__ __hip_bfloat16 Asp[4 * 129 * 8];
  __shared__ __hip_bfloat16 Bsp[4 * 129 * 8];
  int z = blockIdx.z;
  A += (long)(z >> zshift) * sA1 + (long)(z & zmask) * sA2;
  BT += (long)(z >> zshift) * sB1 + (long)(z & zmask) * sB2;
  int tid = threadIdx.x;
  int lane = tid & 63, w = tid >> 6;
  int wr = w >> 1, wc = w & 1;
  int l16 = lane & 15, q = lane >> 4;
  int m0 = blockIdx.y << 7, n0 = blockIdx.x << 7;

  int fm = tid >> 2, fq = tid & 3;
  const __hip_bfloat16* Ap0 = A + (long)(m0 + fm) * lda + fq * 8;
  const __hip_bfloat16* Ap1 = A + (long)(m0 + fm + 64) * lda + fq * 8;
  const __hip_bfloat16* Bp0 = BT + (long)(n0 + fm) * ldb + fq * 8;
  const __hip_bfloat16* Bp1 = BT + (long)(n0 + fm + 64) * ldb + fq * 8;
  __hip_bfloat16* Aw0 = &Asp[(fq * 129 + fm) * 8];
  __hip_bfloat16* Aw1 = &Asp[(fq * 129 + fm + 64) * 8];
  __hip_bfloat16* Bw0 = &Bsp[(fq * 129 + fm) * 8];
  __hip_bfloat16* Bw1 = &Bsp[(fq * 129 + fm + 64) * 8];

  f4 acc[4][4];
#pragma unroll
  for (int i = 0; i < 4; i++)
#pragma unroll
    for (int j = 0; j < 4; j++) acc[i][j] = (f4){0.f, 0.f, 0.f, 0.f};

  b8 pa0 = *(const b8*)Ap0, pa1 = *(const b8*)Ap1;
  b8 pb0 = *(const b8*)Bp0, pb1 = *(const b8*)Bp1;
  for (int k0 = 0; k0 < K; k0 += 32) {
    __syncthreads();
    *(b8*)Aw0 = pa0; *(b8*)Aw1 = pa1;
    *(b8*)Bw0 = pb0; *(b8*)Bw1 = pb1;
    __syncthreads();
    int k1 = k0 + 32;
    if (k1 < K) {
      pa0 = *(const b8*)(Ap0 + k1); pa1 = *(const b8*)(Ap1 + k1);
      pb0 = *(const b8*)(Bp0 + k1); pb1 = *(const b8*)(Bp1 + k1);
    }
    b8 af[4], bf[4];
#pragma unroll
    for (int i = 0; i < 4; i++)
      af[i] = *(const b8*)&Asp[(q * 129 + wr * 64 + i * 16 + l16) * 8];
#pragma unroll
    for (int j = 0; j < 4; j++)
      bf[j] = *(const b8*)&Bsp[(q * 129 + wc * 64 + j * 16 + l16) * 8];
#pragma unroll
    for (int i = 0; i < 4; i++)
#pragma unroll
      for (int j = 0; j < 4; j++)
        acc[i][j] = __builtin_amdgcn_mfma_f32_16x16x32_bf16(af[i], bf[j], acc[i][j], 0, 0, 0);
  }
  if (EPI == 4) {
    // transposed bf16 write: C[b][n][l], b = m>>8, l = m&255, 4 l's per lane
#pragma unroll
    for (int j = 0; j < 4; j++) {
      int n = n0 + wc * 64 + j * 16 + l16;
#pragma unroll
      for (int i = 0; i < 4; i++) {
        int m = m0 + wr * 64 + i * 16 + (q << 2);
        __hip_bfloat16 t4[4];
#pragma unroll
        for (int r = 0; r < 4; r++) t4[r] = __float2bfloat16(acc[i][j][r]);
        long bidx = (long)(m >> 8) * sC + (long)n * cL + (m & 255);
        *(uint2*)&((__hip_bfloat16*)Cv)[bidx] = *(uint2*)t4;
      }
    }
    return;
  }
  long cz = (long)(z >> czdiv) * sC;
#pragma unroll
  for (int j = 0; j < 4; j++) {
    int n = n0 + wc * 64 + j * 16 + l16;
    float bv = BIAS ? bias[n] : 0.f;
#pragma unroll
    for (int i = 0; i < 4; i++) {
#pragma unroll
      for (int r = 0; r < 4; r++) {
        int m = m0 + wr * 64 + i * 16 + q * 4 + r;
        long idx = cz + (long)m * ldc + n;
        float v = acc[i][j][r] + bv;
        if (EPI == 0) {
          if (RELU) v = fmaxf(v, 0.f);
          if (OBF)
            ((__hip_bfloat16*)Cv)[idx] = __float2bfloat16(v);
          else
            ((float*)Cv)[idx] = v;
        } else if (EPI == 3) {
          atomicAdd(&((float*)Cv)[idx], v);
        } else {
          // EPI==2: v = Hout = relu(acc+bias); H' = H + sig(H)*(Hout - H)
          v = fmaxf(v, 0.f);
          float h = auxf[idx];
          float g = sigf(h);
          float o = h + g * (v - h);
          auxf[idx] = o;
          auxb[idx] = __float2bfloat16(o);
        }
      }
    }
  }
}

// ======== dual adjacency GEMM: Isem/Ilat share BT; fused I_com epilogue ========
// C1 = adjag @ HW + b ; C2 = adjlat @ HW + b ; Icb = bf16(C1 + 0.5*sig(C2)*(C2-C1))
// z = batch. A1,A2: (b,L,L) bf16, BT: HW^T (b,D,L) bf16. K = 256.
__global__ __launch_bounds__(256, 2) void bgemm_dual(
    const __hip_bfloat16* __restrict__ A1g, const __hip_bfloat16* __restrict__ A2g,
    const __hip_bfloat16* __restrict__ BTg, float* __restrict__ IsemF,
    __hip_bfloat16* __restrict__ Icb, const float* __restrict__ bias,
    int write_isem) {
  __shared__ __hip_bfloat16 A1sp[4 * 129 * 8];
  __shared__ __hip_bfloat16 A2sp[4 * 129 * 8];
  __shared__ __hip_bfloat16 Bsp[4 * 129 * 8];
  int z = blockIdx.z;
  const __hip_bfloat16* A1 = A1g + (long)z * cLL;
  const __hip_bfloat16* A2 = A2g + (long)z * cLL;
  const __hip_bfloat16* BT = BTg + (long)z * cLD;
  int tid = threadIdx.x;
  int lane = tid & 63, w = tid >> 6;
  int wr = w >> 1, wc = w & 1;
  int l16 = lane & 15, q = lane >> 4;
  int m0 = blockIdx.y << 7, n0 = blockIdx.x << 7;

  int fm = tid >> 2, fq = tid & 3;
  const __hip_bfloat16* A1p0 = A1 + (long)(m0 + fm) * cL + fq * 8;
  const __hip_bfloat16* A1p1 = A1p0 + 64L * cL;
  const __hip_bfloat16* A2p0 = A2 + (long)(m0 + fm) * cL + fq * 8;
  const __hip_bfloat16* A2p1 = A2p0 + 64L * cL;
  const __hip_bfloat16* Bp0 = BT + (long)(n0 + fm) * cL + fq * 8;
  const __hip_bfloat16* Bp1 = Bp0 + 64L * cL;
  __hip_bfloat16* w10 = &A1sp[(fq * 129 + fm) * 8];
  __hip_bfloat16* w11 = &A1sp[(fq * 129 + fm + 64) * 8];
  __hip_bfloat16* w20 = &A2sp[(fq * 129 + fm) * 8];
  __hip_bfloat16* w21 = &A2sp[(fq * 129 + fm + 64) * 8];
  __hip_bfloat16* wb0 = &Bsp[(fq * 129 + fm) * 8];
  __hip_bfloat16* wb1 = &Bsp[(fq * 129 + fm + 64) * 8];

  f4 ac1[4][4], ac2[4][4];
#pragma unroll
  for (int i = 0; i < 4; i++)
#pragma unroll
    for (int j = 0; j < 4; j++) {
      ac1[i][j] = (f4){0.f, 0.f, 0.f, 0.f};
      ac2[i][j] = (f4){0.f, 0.f, 0.f, 0.f};
    }

  b8 p10 = *(const b8*)A1p0, p11 = *(const b8*)A1p1;
  b8 p20 = *(const b8*)A2p0, p21 = *(const b8*)A2p1;
  b8 pb0 = *(const b8*)Bp0, pb1 = *(const b8*)Bp1;
  for (int k0 = 0; k0 < cL; k0 += 32) {
    __syncthreads();
    *(b8*)w10 = p10; *(b8*)w11 = p11;
    *(b8*)w20 = p20; *(b8*)w21 = p21;
    *(b8*)wb0 = pb0; *(b8*)wb1 = pb1;
    __syncthreads();
    int k1 = k0 + 32;
    if (k1 < cL) {
      p10 = *(const b8*)(A1p0 + k1); p11 = *(const b8*)(A1p1 + k1);
      p20 = *(const b8*)(A2p0 + k1); p21 = *(const b8*)(A2p1 + k1);
      pb0 = *(const b8*)(Bp0 + k1); pb1 = *(const b8*)(Bp1 + k1);
    }
    b8 a1f[4], a2f[4], bf[4];
#pragma unroll
    for (int i = 0; i < 4; i++) {
      a1f[i] = *(const b8*)&A1sp[(q * 129 + wr * 64 + i * 16 + l16) * 8];
      a2f[i] = *(const b8*)&A2sp[(q * 129 + wr * 64 + i * 16 + l16) * 8];
    }
#pragma unroll
    for (int j = 0; j < 4; j++)
      bf[j] = *(const b8*)&Bsp[(q * 129 + wc * 64 + j * 16 + l16) * 8];
#pragma unroll
    for (int i = 0; i < 4; i++)
#pragma unroll
      for (int j = 0; j < 4; j++) {
        ac1[i][j] = __builtin_amdgcn_mfma_f32_16x16x32_bf16(a1f[i], bf[j], ac1[i][j], 0, 0, 0);
        ac2[i][j] = __builtin_amdgcn_mfma_f32_16x16x32_bf16(a2f[i], bf[j], ac2[i][j], 0, 0, 0);
      }
  }
  long cz = (long)z * cLD;
#pragma unroll
  for (int j = 0; j < 4; j++) {
    int n = n0 + wc * 64 + j * 16 + l16;
    float bv = bias[n];
#pragma unroll
    for (int i = 0; i < 4; i++) {
#pragma unroll
      for (int r = 0; r < 4; r++) {
        int m = m0 + wr * 64 + i * 16 + q * 4 + r;
        long idx = cz + (long)m * cD + n;
        float is = ac1[i][j][r] + bv;
        float il = ac2[i][j][r] + bv;
        float g = 0.5f * sigf(il);
        Icb[idx] = __float2bfloat16(is + g * (il - is));
        if (write_isem) IsemF[idx] = is;
      }
    }
  }
}

// ---------------- 7 weight convert+transpose in one dispatch ----------------
__global__ void k_wconv7(const float* __restrict__ s0, const float* __restrict__ s1,
                         const float* __restrict__ s2, const float* __restrict__ s3,
                         const float* __restrict__ s4, const float* __restrict__ s5,
                         const float* __restrict__ s6, __hip_bfloat16* __restrict__ dst) {
  const float* srcs[7] = {s0, s1, s2, s3, s4, s5, s6};
  const float* src = srcs[blockIdx.z];
  __hip_bfloat16* d = dst + (long)blockIdx.z * cD * cD;
  __shared__ float t[32][33];
  int k0 = blockIdx.x * 32, n0 = blockIdx.y * 32;
  int tx = threadIdx.x, ty = threadIdx.y;
#pragma unroll
  for (int i = 0; i < 32; i += 8) t[ty + i][tx] = src[(long)(k0 + ty + i) * cD + n0 + tx];
  __syncthreads();
#pragma unroll
  for (int i = 0; i < 32; i += 8)
    d[(long)(n0 + ty + i) * cD + k0 + tx] = __float2bfloat16(t[tx][ty + i]);
}

// ---------------- embedding + layernorm + fused root dot; pre-LN x for l==0 ----------------
__global__ __launch_bounds__(256) void k_gcnin(
    const int* __restrict__ tbi, const int* __restrict__ bsi,
    const float* __restrict__ tok, const float* __restrict__ seg,
    const float* __restrict__ ln_a, const float* __restrict__ ln_b,
    const float* __restrict__ root_w,
    float* __restrict__ gcn_in, __hip_bfloat16* __restrict__ gib,
    float* __restrict__ x64, float* __restrict__ e1) {
  long bl = blockIdx.x;
  int t = tbi[bl], s = bsi[bl];
  const float* tr = tok + (long)t * cD;
  const float* sr = seg + (long)s * cD;
  float x[3];
  float ls = 0.f;
#pragma unroll
  for (int i = 0; i < 3; i++) {
    int d = threadIdx.x + (i << 8);
    x[i] = tr[d] + sr[d];
    ls += x[i];
  }
  if ((bl & 255) == 0) {
#pragma unroll
    for (int i = 0; i < 3; i++) x64[(bl >> 8) * cD + threadIdx.x + (i << 8)] = x[i];
  }
  float mean = blockSum(ls) * (1.f / 768.f);
  float lv = 0.f;
#pragma unroll
  for (int i = 0; i < 3; i++) { float c = x[i] - mean; lv += c * c; }
  float var = blockSum(lv) * (1.f / 767.f);
  float inv = 1.f / (sqrtf(var) + 1e-6f);
  float rdot = 0.f;
#pragma unroll
  for (int i = 0; i < 3; i++) {
    int d = threadIdx.x + (i << 8);
    float v = ln_a[d] * (x[i] - mean) * inv + ln_b[d];
    gcn_in[bl * cD + d] = v;
    gib[bl * cD + d] = __float2bfloat16(v);
    rdot += v * root_w[d];
  }
  float tot = blockSum(rdot);
  if (threadIdx.x == 0) e1[bl] = tot;
}

// ---------------- pooled GEMV partials ----------------
__global__ __launch_bounds__(256) void k_pool1(
    const float* __restrict__ x64, const float* __restrict__ pw,
    float* __restrict__ pacc) {
  __shared__ float pws[48][256];
  __shared__ float xs[16][48];
  int i0 = blockIdx.x * 48, j0 = blockIdx.y * 256, b0 = blockIdx.z * 16;
  for (int r = 0; r < 48; r++) pws[r][threadIdx.x] = pw[(long)(i0 + r) * cD + j0 + threadIdx.x];
  for (int idx = threadIdx.x; idx < 16 * 48; idx += 256)
    xs[idx / 48][idx % 48] = x64[(long)(b0 + idx / 48) * cD + i0 + idx % 48];
  __syncthreads();
  int j = threadIdx.x;
  for (int b = 0; b < 16; b++) {
    float acc = 0.f;
#pragma unroll 8
    for (int i = 0; i < 48; i++) acc += xs[b][i] * pws[i][j];
    atomicAdd(&pacc[(long)(b0 + b) * cD + j0 + j], acc);
  }
}
__global__ __launch_bounds__(256) void k_pool2(
    const float* __restrict__ pacc, const float* __restrict__ pb,
    float* __restrict__ pooled) {
  int b = blockIdx.x;
#pragma unroll
  for (int c = 0; c < 3; c++) {
    int j = (c << 8) + threadIdx.x;
    pooled[(long)b * cD + j] = tanhf(pacc[(long)b * cD + j] + pb[j]);
  }
}

// ---------------- dep LUT ----------------
__global__ __launch_bounds__(256) void k_s45(
    const float* __restrict__ dep_emb, const float* __restrict__ fc1w,
    const float* __restrict__ fc1b, const float* __restrict__ fc2w,
    const float* __restrict__ fc2b, float* __restrict__ s45) {
  int t = blockIdx.x;
  __shared__ float e[300];
  for (int i = threadIdx.x; i < 300; i += 256) e[i] = dep_emb[t * 300 + i];
  __syncthreads();
  int j = threadIdx.x;
  float h = fc1b[j];
  for (int i = 0; i < 300; i++) h += e[i] * fc1w[i * 256 + j];
  h = fmaxf(h, 0.f);
  float tot = blockSum(h * fc2w[j]);
  if (threadIdx.x == 0) s45[t] = tot + fc2b[0];
}

__global__ __launch_bounds__(256) void k_depfeat(
    const int* __restrict__ ori, const float* __restrict__ src_mask,
    const float* __restrict__ s45, float* __restrict__ dep_feat) {
  int b = blockIdx.x, l = threadIdx.x;
  float smv = (l == 0) ? 1.f : src_mask[b * cL + l];
  float sc = s45[ori[b * cL + l]] * smv + (1.f - smv) * (-1e30f);
  float mx = blockMax(sc);
  float ex = expf(sc - mx);
  float sum = blockSum(ex);
  dep_feat[b * cL + l] = ex / sum;
}

// ---------------- bias concat for fused projection ----------------
__global__ void k_bcat(const float* __restrict__ a, const float* __restrict__ b,
                       const float* __restrict__ c, const float* __restrict__ d,
                       float* __restrict__ o) {
  int i = blockIdx.x * 256 + threadIdx.x;
  float v = (i < 768) ? a[i] : (i < 1536) ? b[i - 768] : (i < 2304) ? c[i - 1536] : d[i - 2304];
  o[i] = v;
}

// ---------------- adj_ag softmax (bf16 scores in) ----------------
__global__ __launch_bounds__(256) void k_adjag_sm(
    const __hip_bfloat16* __restrict__ scores, const float* __restrict__ src_mask,
    __hip_bfloat16* __restrict__ adjag) {
  int b = blockIdx.x >> 8, i = blockIdx.x & 255;
  int tid = threadIdx.x, wave = tid >> 6, lane = tid & 63;
  __shared__ float accs[4][256];
  const float scale = 1.f / (sqrtf(96.f) + 1e-9f);
  float smj[4], acc[4];
#pragma unroll
  for (int c = 0; c < 4; c++) {
    int j = c * 64 + lane;
    smj[c] = (j == 0) ? 1.f : src_mask[b * cL + j];
    acc[c] = 0.f;
  }
  for (int hh = 0; hh < 2; hh++) {
    int h = wave * 2 + hh;
    const __hip_bfloat16* row = scores + (((long)(b * 8 + h)) * cL + i) * cL;
    float s[4], m = -1e30f;
#pragma unroll
    for (int c = 0; c < 4; c++) {
      s[c] = (smj[c] == 0.f) ? -1e9f : __bfloat162float(row[c * 64 + lane]) * scale;
      m = fmaxf(m, s[c]);
    }
    m = wmax_all(m);
    float es = 0.f;
#pragma unroll
    for (int c = 0; c < 4; c++) { s[c] = expf(s[c] - m); es += s[c]; }
    es = wsum_all(es);
    float inv = 1.f / es;
#pragma unroll
    for (int c = 0; c < 4; c++) acc[c] += s[c] * inv;
  }
#pragma unroll
  for (int c = 0; c < 4; c++) accs[wave][c * 64 + lane] = acc[c];
  __syncthreads();
  int j = tid;
  float tot = accs[0][j] + accs[1][j] + accs[2][j] + accs[3][j];
  float smi = (i == 0) ? 1.f : src_mask[b * cL + i];
  float v = (j == i) ? 1.f : tot * 0.125f;
  adjag[((long)b * cL + i) * cL + j] = __float2bfloat16(v * smi);
}

// ---------------- adj_latent softmax (f32 split-K scores) + inlined dep_adj ----------------
__global__ __launch_bounds__(256) void k_adjlat_sm(
    const float* __restrict__ latsc, const int* __restrict__ head,
    const float* __restrict__ df, const float* __restrict__ src_mask,
    __hip_bfloat16* __restrict__ adjlat) {
  int b = blockIdx.x >> 8, i = blockIdx.x & 255;
  int j = threadIdx.x;
  float smj = (j == 0) ? 1.f : src_mask[b * cL + j];
  float dep = 1.f;
  if (j >= 1 && head[b * cL + j - 1] == i) dep = df[b * cL + j - 1];
  if (i >= 1 && j == head[b * cL + i - 1]) dep = df[b * cL + i - 1];
  float s = latsc[((long)b * cL + i) * cL + j] * (1.f / sqrtf(768.f)) +
            dep + (1.f - smj) * (-10000.f);
  float mx = blockMax(s);
  float ex = expf(s - mx);
  float sum = blockSum(ex);
  float p = ex / sum;
  float smi = (i == 0) ? 1.f : src_mask[b * cL + i];
  adjlat[((long)b * cL + i) * cL + j] = __float2bfloat16(((j == i) ? 1.f : p) * smi);
}

// ---------------- wave-per-row dot ----------------
__global__ __launch_bounds__(256) void k_rowdot(
    const float* __restrict__ X, const float* __restrict__ w, long wstride,
    float* __restrict__ e) {
  int r = blockIdx.x * 4 + (threadIdx.x >> 6);
  int lane = threadIdx.x & 63;
  const float4* row = (const float4*)(X + (long)r * cD);
  const float4* wp = (const float4*)(w + (long)(r >> 8) * wstride);
  float s = 0.f;
#pragma unroll
  for (int c = 0; c < 3; c++) {
    int idx = c * 64 + lane;
    float4 a = row[idx], b = wp[idx];
    s += a.x * b.x + a.y * b.y + a.z * b.z + a.w * b.w;
  }
  s = wsum(s);
  if (lane == 0) e[r] = s;
}

// ---------------- root loss ----------------
__global__ __launch_bounds__(256) void k_root2(
    const float* __restrict__ e1, const float* __restrict__ src_mask,
    const float* __restrict__ aspect_mask, float* __restrict__ out_loss) {
  int b = blockIdx.x, l = threadIdx.x;
  float r = e1[b * cL + l];
  float smv = (l == 0) ? 1.f : src_mask[b * cL + l];
  float sc = r * smv + (1.f - smv) * (-1e30f);
  float mx = blockMax(sc);
  float ex = expf(sc - mx);
  float sum = blockSum(ex);
  float p = ex / sum;
  float tot = blockSum(p * aspect_mask[b * cL + l]);
  if (l == 0) atomicAdd(out_loss, -logf(tot + 1e-9f) * (1.f / 64.f));
}

// ---------------- lexicon loss ----------------
__global__ __launch_bounds__(256) void k_lex2(
    const float* __restrict__ e2, const float* __restrict__ src_mask,
    const float* __restrict__ lex, float* __restrict__ out_loss) {
  int b = blockIdx.x, l = threadIdx.x;
  float e = e2[b * cL + l];
  float mx = blockMax(e);
  float ex = expf(e - mx);
  float sum = blockSum(ex);
  float mult = (l == 0) ? 0.f : src_mask[b * cL + l];
  float lw = ex / sum * 50.f * mult;
  float d2 = lw - lex[b * cL + l];
  float tot = blockSum(d2 * d2);
  if (l == 0) atomicAdd(out_loss, tot * (1.f / (64.f * 256.f)));
}

// ---------------- hlsum partials ----------------
__global__ __launch_bounds__(256) void k_hl(
    const float* __restrict__ H, const float* __restrict__ src_mask,
    float* __restrict__ hlsum) {
  int b = blockIdx.z, d = (blockIdx.y << 8) + threadIdx.x, l0 = blockIdx.x * 32;
  float acc = 0.f;
  for (int l = l0; l < l0 + 32; l++) {
    float smv = (l == 0) ? 1.f : src_mask[b * cL + l];
    acc += H[((long)b * cL + l) * cD + d] * smv;
  }
  atomicAdd(&hlsum[(long)b * cD + d], acc);
}

// ---------------- attn weights + asum ----------------
__global__ __launch_bounds__(256) void k_attnw(
    const float* __restrict__ sraw, const float* __restrict__ src_mask,
    const float* __restrict__ am, float* __restrict__ wgt, float* __restrict__ asum) {
  int b = blockIdx.x, k = threadIdx.x;
  float smk = (k == 0) ? 1.f : src_mask[b * cL + k];
  float s = sraw[b * cL + k] * smk * 0.001f;
  float mx = blockMax(s);
  float ex = expf(s - mx);
  float sum = blockSum(ex);
  wgt[b * cL + k] = ex / sum;
  float a = blockSum(am[b * cL + k]);
  if (k == 0) asum[b] = a;
}

// ---------------- fused outputs+sempool partials ----------------
__global__ __launch_bounds__(256) void k_wsum(
    const float* __restrict__ Isem, const float* __restrict__ wgt,
    const float* __restrict__ am, float* __restrict__ outputs,
    float* __restrict__ sempool) {
  int b = blockIdx.z, d = (blockIdx.y << 8) + threadIdx.x, l0 = blockIdx.x * 32;
  float accO = 0.f, accS = 0.f;
  for (int l = l0; l < l0 + 32; l++) {
    float v = Isem[((long)b * cL + l) * cD + d];
    accO += wgt[b * cL + l] * v;
    accS += am[b * cL + l] * v;
  }
  atomicAdd(&outputs[(long)b * cD + d], accO);
  atomicAdd(&sempool[(long)b * cD + d], accS);
}

// ---------------- logits ----------------
__global__ __launch_bounds__(256) void k_logits(
    const float* __restrict__ outputs, const float* __restrict__ sempool,
    const float* __restrict__ pooled, const float* __restrict__ asum,
    const float* __restrict__ cw, const float* __restrict__ cb,
    float* __restrict__ out) {
  int b = blockIdx.x;
  float inv = 1.f / (asum[b] + 1e-9f);
  float a0 = 0.f, a1 = 0.f, a2 = 0.f;
  for (int i = threadIdx.x; i < 3 * cD; i += 256) {
    float f = (i < cD) ? outputs[(long)b * cD + i]
              : (i < 2 * cD) ? sempool[(long)b * cD + i - cD] * inv
                             : pooled[(long)b * cD + i - 2 * cD];
    a0 += f * cw[i * 3 + 0];
    a1 += f * cw[i * 3 + 1];
    a2 += f * cw[i * 3 + 2];
  }
  a0 = blockSum(a0);
  a1 = blockSum(a1);
  a2 = blockSum(a2);
  if (threadIdx.x == 0) {
    out[b * 3 + 0] = a0 + cb[0];
    out[b * 3 + 1] = a1 + cb[1];
    out[b * 3 + 2] = a2 + cb[2];
  }
}

extern "C" void kernel_launch(void* const* d_in, const int* in_sizes, int n_in,
                              void* d_out, int out_size, void* d_ws, size_t ws_size,
                              hipStream_t stream) {
  const int* tbi = (const int*)d_in[0];
  const int* bsi = (const int*)d_in[1];
  const float* src_mask = (const float*)d_in[3];
  const float* aspect_mask = (const float*)d_in[4];
  const float* lex = (const float*)d_in[5];
  const int* ori = (const int*)d_in[6];
  const int* head = (const int*)d_in[7];
  const float* tok_emb = (const float*)d_in[8];
  const float* seg_emb = (const float*)d_in[9];
  const float* pool_w = (const float*)d_in[10];
  const float* pool_b = (const float*)d_in[11];
  const float* ln_a = (const float*)d_in[12];
  const float* ln_b = (const float*)d_in[13];
  const float* dep_emb = (const float*)d_in[14];
  const float* fc1_w = (const float*)d_in[15];
  const float* fc1_b = (const float*)d_in[16];
  const float* fc2_w = (const float*)d_in[17];
  const float* fc2_b = (const float*)d_in[18];
  const float* aq_w = (const float*)d_in[19];
  const float* aq_b = (const float*)d_in[20];
  const float* ak_w = (const float*)d_in[21];
  const float* ak_b = (const float*)d_in[22];
  const float* lq_w = (const float*)d_in[23];
  const float* lq_b = (const float*)d_in[24];
  const float* lk_w = (const float*)d_in[25];
  const float* lk_b = (const float*)d_in[26];
  const float* root_w = (const float*)d_in[27];
  const float* gcn_w = (const float*)d_in[28];
  const float* gcn_b = (const float*)d_in[29];
  const float* fc3_w = (const float*)d_in[30];
  const float* fc3_b = (const float*)d_in[31];
  const float* cls_w = (const float*)d_in[32];
  const float* cls_b = (const float*)d_in[33];
  const float* vlin_w = (const float*)d_in[34];

  float* out = (float*)d_out;
  float* ws = (float*)d_ws;
  // fp32 region
  float* gcnH = ws;            // BLD (gcn_in -> H_l)
  float* Isem = gcnH + BLD;    // BLD  (also latsc f32 alias pre-loop)
  float* depfeat = Isem + BLD;         // B*L
  float* s45 = depfeat + cB * cL;      // 64
  float* pooled = s45 + 64;            // B*D
  float* x64 = pooled + cB * cD;       // B*D
  float* hlsum = x64 + cB * cD;        // B*D  --- zeroed region start
  float* outputs = hlsum + cB * cD;    // B*D
  float* sempool = outputs + cB * cD;  // B*D
  float* pacc = sempool + cB * cD;     // B*D  --- zeroed region end
  float* e1 = pacc + cB * cD;          // B*L
  float* e2 = e1 + cB * cL;            // B*L
  float* sraw = e2 + cB * cL;          // B*L
  float* wgt = sraw + cB * cL;         // B*L
  float* asum = wgt + cB * cL;         // 64
  float* catb = asum + 64;             // 3072
  float* latsc = Isem;                 // BLL f32 alias (dead until GCN loop)
  // bf16 region
  __hip_bfloat16* gib = (__hip_bfloat16*)(catb + 3072);  // BLD
  __hip_bfloat16* qkb = gib + BLD;             // 4*BLD (q|k|q2|k2, ldc=3072)
  __hip_bfloat16* scores = qkb + 4 * BLD;      // 8*BLL
  __hip_bfloat16* adjag_b = scores + 8 * BLL;  // BLL
  __hip_bfloat16* adjlat_b = adjag_b + BLL;    // BLL
  __hip_bfloat16* wbt = adjlat_b + BLL;        // 7*D*D
  // aliases
  __hip_bfloat16* HWbT = qkb + BLD;     // BLD (HW^T, written directly by EPI=4)
  __hip_bfloat16* Icb = qkb + 2 * BLD;  // BLD

  hipMemsetAsync((char*)d_out + 192 * sizeof(float), 0, 2 * sizeof(float), stream);
  hipMemsetAsync(hlsum, 0, 4 * cB * cD * sizeof(float), stream);
  hipMemsetAsync(latsc, 0, BLL * sizeof(float), stream);  // split-K accumulator

  // ---- prologue ----
  k_gcnin<<<cB * cL, 256, 0, stream>>>(tbi, bsi, tok_emb, seg_emb, ln_a, ln_b,
                                       root_w, gcnH, gib, x64, e1);
  k_s45<<<45, 256, 0, stream>>>(dep_emb, fc1_w, fc1_b, fc2_w, fc2_b, s45);
  k_depfeat<<<cB, 256, 0, stream>>>(ori, src_mask, s45, depfeat);
  k_pool1<<<dim3(16, 3, 4), 256, 0, stream>>>(x64, pool_w, pacc);
  k_pool2<<<cB, 256, 0, stream>>>(pacc, pool_b, pooled);
  k_bcat<<<12, 256, 0, stream>>>(aq_b, ak_b, lq_b, lk_b, catb);
  k_wconv7<<<dim3(24, 24, 7), dim3(32, 8), 0, stream>>>(
      aq_w, ak_w, lq_w, lk_w, gcn_w, gcn_w + (long)cD * cD, fc3_w, wbt);

  const long DD = (long)cD * cD;
  const long LD = cLD, LL = cLL;
  const long LP = (long)cL * 3072;  // qkb batch stride

  // ---- fused 4-way projection: qkb = gib @ [aq|ak|lq|lk] + catb ----
  bgemm<1, 0, 1, 0><<<dim3(24, 128, 1), 256, 0, stream>>>(
      gib, wbt, qkb, catb, nullptr, nullptr, cD, cD, cD, 3072,
      0, 0, 0, 0, 0, 0, 0, 0);

  // ---- head scores (bf16 out) + adj_ag softmax ----
  bgemm<1, 0, 0, 0><<<dim3(2, 2, cB * 8), 256, 0, stream>>>(
      qkb, qkb + 768, scores, nullptr, nullptr, nullptr,
      96, 3072, 3072, cL, 3, 7, LP, 96, LP, 96, LL, 0);
  k_adjag_sm<<<cB * cL, 256, 0, stream>>>(scores, src_mask, adjag_b);

  // ---- latent scores: split-K (2x384) f32 atomicAdd + adj_latent softmax ----
  bgemm<0, 0, 0, 3><<<dim3(2, 2, cB * 2), 256, 0, stream>>>(
      qkb + 1536, qkb + 2304, latsc, nullptr, nullptr, nullptr,
      384, 3072, 3072, cL, 1, 1, LP, 384, LP, 384, LL, 1);
  k_adjlat_sm<<<cB * cL, 256, 0, stream>>>(latsc, head, depfeat, src_mask, adjlat_b);

  // ---- root loss (e1 fused into k_gcnin) ----
  k_root2<<<cB, 256, 0, stream>>>(e1, src_mask, aspect_mask, out + 192);

  // ---- GCN loop ----
  for (int layer = 0; layer < 2; layer++) {
    const float* bb = gcn_b + (long)layer * cD;
    // HW^T = (H @ W)^T written directly (EPI=4), layout (b, d, l)
    bgemm<1, 0, 0, 4><<<dim3(6, 128, 1), 256, 0, stream>>>(
        gib, wbt + (4 + layer) * DD, HWbT, nullptr, nullptr, nullptr,
        cD, cD, cD, cD, 0, 0, 0, 0, 0, 0, LD, 0);
    // dual adjacency GEMM + fused I_com epilogue (writes Isem f32 on last layer)
    bgemm_dual<<<dim3(6, 2, cB), 256, 0, stream>>>(
        adjag_b, adjlat_b, HWbT, Isem, Icb, bb, layer == 1 ? 1 : 0);
    // fc3 GEMM with fused H-gate epilogue: updates gcnH (f32) + gib (bf16)
    bgemm<0, 1, 1, 2><<<dim3(6, 128, 1), 256, 0, stream>>>(
        Icb, wbt + 6 * DD, nullptr, fc3_b, gcnH, gib,
        cD, cD, cD, cD, 0, 0, 0, 0, 0, 0, 0, 0);
  }

  // ---- tail ----
  k_hl<<<dim3(8, 3, cB), 256, 0, stream>>>(gcnH, src_mask, hlsum);
  k_rowdot<<<cB * cL / 4, 256, 0, stream>>>(Isem, hlsum, cD, sraw);
  k_attnw<<<cB, 256, 0, stream>>>(sraw, src_mask, aspect_mask, wgt, asum);
  k_wsum<<<dim3(8, 3, cB), 256, 0, stream>>>(Isem, wgt, aspect_mask, outputs, sempool);
  k_logits<<<cB, 256, 0, stream>>>(outputs, sempool, pooled, asum, cls_w, cls_b, out);
  k_rowdot<<<cB * cL / 4, 256, 0, stream>>>(gcnH, vlin_w, 0, e2);
  k_lex2<<<cB, 256, 0, stream>>>(e2, src_mask, lex, out + 193);
}